// Round 7
// baseline (165.061 us; speedup 1.0000x reference)
//
#include <hip/hip_runtime.h>

// ConvNet_STDP — 5 regular kernels, stream-ordered, NO cooperative launch.
//
// Verified (rounds 1-6, absmax 0.0):
//  * STDP provably inert -> weight outputs are clip(w_init, 0, 1).
//  * Network dies at t=0 for this input (all m2 cleared) -> z5=z6=z9=0 for
//    t>=1 -> head follows closed-form LI decay.
//  * Batch independence: recurrence has NO cross-batch coupling -> fallback
//    (alive inputs) runs per-batch in one block; no grid syncs anywhere.
//  * R6 diagnosis: k2 = 85us of 126 -> LDS byte-read bound (256 ds_read_u8
//    per item) + 2 blocks/CU. This round: z3 rows packed to 25-bit masks
//    (inner loop = cndmask+add, zero LDS reads), grid 2400; k1 split 8
//    lanes/cell with 28 independent accumulators, grid 975.
//  * Exactness: fmaf(1,w,s)==s+w and fmaf(0,w,s)==s bitwise; accumulation
//    order (i outer, j inner, per-output chain) unchanged from the
//    absmax-0.0 rounds.

#define T_STEPS 30
#define BATCH   32
#define H_IN    240
#define W_IN    160
#define C1      4
#define H1      236
#define W1O     156
#define H3      39
#define W3      25
#define C2      20
#define H2      24
#define W2O     10
#define C3      10
#define H8      8

#define N1PB   (C1*H1*W1O)         // 147,264 per-batch conv1 positions
#define N_V1   (BATCH*N1PB)        // 4,712,448
#define N_V2PB (C2*H2*W2O)         // 4,800
#define N_V2   (BATCH*N_V2PB)      // 153,600
#define Z3PB   (C1*H3*W3)          // 3,900
#define N_Z3   (BATCH*Z3PB)        // 124,800
#define N_POOL (BATCH*H3*W3)       // 31,200
#define N_FEAT (BATCH*C3)          // 320

#define NTHR 256

// ---- K1: fused conv1+pool1 (t=0, stateless) -> z3; init alive2 ----
// 8 lanes per pooled cell; lane q<7 computes window row q (7 wx positions),
// 28 independent accumulators; OR-reduce via shuffle.
__global__ __launch_bounds__(NTHR) void k1_conv1pool(
    const float* __restrict__ x, const float* __restrict__ w1,
    unsigned char* __restrict__ z3, int* alive2)
{
  __shared__ float s_w1[C1*25];
  for (int i = threadIdx.x; i < C1*25; i += NTHR) s_w1[i] = w1[i];
  __syncthreads();
  int it = blockIdx.x*NTHR + threadIdx.x;
  if (it == 0) *alive2 = N_V2;
  int o = it >> 3, q = it & 7;
  int px = o % W3; int tt = o / W3;
  int py = tt % H3; int b = tt / H3;
  unsigned mask = 0;
  if (q < 7) {
    const float* xb = x + (size_t)b*H_IN*W_IN;
    int ybase = py*6 + q;                       // this lane's window row
    float acc[C1][7];
    #pragma unroll
    for (int c = 0; c < C1; ++c)
      #pragma unroll
      for (int wx = 0; wx < 7; ++wx) acc[c][wx] = 0.f;
    #pragma unroll
    for (int i = 0; i < 5; ++i) {
      const float* xp = xb + (size_t)(ybase + i)*W_IN + px*6;
      float xr[11];
      #pragma unroll
      for (int k = 0; k < 11; ++k) xr[k] = xp[k];
      #pragma unroll
      for (int j = 0; j < 5; ++j) {
        float w0 = s_w1[ 0 + i*5 + j];
        float w1v = s_w1[25 + i*5 + j];
        float w2v = s_w1[50 + i*5 + j];
        float w3v = s_w1[75 + i*5 + j];
        #pragma unroll
        for (int wx = 0; wx < 7; ++wx) {
          float xv = xr[wx + j];
          acc[0][wx] = fmaf(xv, w0,  acc[0][wx]);
          acc[1][wx] = fmaf(xv, w1v, acc[1][wx]);
          acc[2][wx] = fmaf(xv, w2v, acc[2][wx]);
          acc[3][wx] = fmaf(xv, w3v, acc[3][wx]);
        }
      }
    }
    #pragma unroll
    for (int c = 0; c < C1; ++c)
      #pragma unroll
      for (int wx = 0; wx < 7; ++wx)
        mask |= (acc[c][wx] >= 10.f) ? (1u << c) : 0u;
  }
  mask |= __shfl_xor(mask, 1, 64);
  mask |= __shfl_xor(mask, 2, 64);
  mask |= __shfl_xor(mask, 4, 64);
  if (q == 0 && o < N_POOL) {
    unsigned char* zp = z3 + (size_t)b*Z3PB + py*W3 + px;
    zp[0]        =  mask       & 1;
    zp[H3*W3]    = (mask >> 1) & 1;
    zp[2*H3*W3]  = (mask >> 2) & 1;
    zp[3*H3*W3]  = (mask >> 3) & 1;
  }
}

// ---- K2: conv2 + IAF(60) (t=0: v=s, m=1) -> z5; alive2 -= fired ----
// z3 rows packed to 25-bit masks in LDS; inner loop has NO LDS/memory reads
// for activations. Grid 2400 = 75 blocks x 32 batches, 1 item/thread.
__global__ __launch_bounds__(NTHR) void k2_conv2(
    const unsigned char* __restrict__ z3, const float* __restrict__ w2,
    unsigned char* __restrict__ z5, int* alive2)
{
  __shared__ unsigned s_mask[C1*H3];            // 156 packed rows
  const int b  = blockIdx.x & 31;               // grid multiple of 32
  const int wb = blockIdx.x >> 5;
  const int tid = threadIdx.x;
  if (tid < C1*H3) {                            // row tid -> bytes tid*25
    const unsigned char* rp = z3 + (size_t)b*Z3PB + tid*W3;
    unsigned m = 0;
    #pragma unroll
    for (int k = 0; k < W3; ++k) m |= (rp[k] ? 1u : 0u) << k;
    s_mask[tid] = m;
  }
  __syncthreads();
  int it = wb*NTHR + tid;                       // 0..19199 exactly
  int o = it >> 2, ci = it & 3;                 // 4 lanes per output
  int c  = o / (H2*W2O);
  int r  = o - c*(H2*W2O);
  int oy = r / W2O, ox = r - (r/W2O)*W2O;
  const float* wp2 = w2 + ((size_t)c*C1 + ci)*256;
  float s = 0.f;
  #pragma unroll
  for (int i = 0; i < 16; ++i) {
    unsigned m = s_mask[ci*H3 + oy + i] >> ox;  // bits 0..15 = window row
    const float* wp = wp2 + i*16;
    #pragma unroll
    for (int j = 0; j < 16; ++j)
      s += (m & (1u << j)) ? wp[j] : 0.f;       // == fmaf(z, w, s) bitwise
  }
  s += __shfl_xor(s, 1, 64);
  s += __shfl_xor(s, 2, 64);
  int nf = 0;
  if (ci == 0) {
    unsigned char sp = (s >= 60.0f) ? 1 : 0;
    z5[b*N_V2PB + o] = sp;
    nf = sp;
  }
  #pragma unroll
  for (int o2 = 1; o2 < 64; o2 <<= 1) nf += __shfl_xor(nf, o2, 64);
  if ((tid & 63) == 0 && nf) atomicSub(alive2, nf);
}

// ---- K3: conv3 (pool2 folded) + IAF(2) (t=0) -> z9[0]. One block/batch ----
__global__ __launch_bounds__(NTHR) void k3_conv3(
    const unsigned char* __restrict__ z5, const float* __restrict__ w3,
    float* __restrict__ z9)
{
  const int b = blockIdx.x, tid = threadIdx.x;
  __shared__ unsigned int s_z5w[N_V2PB/4];
  __shared__ unsigned char s_z8[C3*H8];
  const unsigned int* zsrc = (const unsigned int*)(z5 + (size_t)b*N_V2PB);
  for (int i = tid; i < N_V2PB/4; i += NTHR) s_z5w[i] = zsrc[i];
  __syncthreads();
  const unsigned char* sz = (const unsigned char*)s_z5w;
  for (int it = tid; it < C3*H8*4; it += NTHR) {
    int o = it >> 2, g = it & 3;                // 5-channel group per lane
    int c3 = o >> 3, oy = o & 7;
    float s = 0.f;
    for (int ci = g*5; ci < g*5 + 5; ++ci) {
      const unsigned char* zp = sz + ci*H2*W2O;
      const float* wp = w3 + ((size_t)c3*C2 + ci)*25;
      #pragma unroll
      for (int i = 0; i < 5; ++i) {
        const unsigned char* r0 = zp + (2*(oy + i))*W2O;
        const unsigned char* r1 = r0 + W2O;
        #pragma unroll
        for (int j = 0; j < 5; ++j) {
          unsigned char zv = r0[2*j] | r0[2*j+1] | r1[2*j] | r1[2*j+1];
          s = fmaf((float)zv, wp[i*5 + j], s);
        }
      }
    }
    s += __shfl_xor(s, 1, 64);
    s += __shfl_xor(s, 2, 64);
    if (g == 0) s_z8[o] = (s >= 2.0f) ? 1 : 0;
  }
  __syncthreads();
  if (tid < C3) {
    unsigned char r = 0;
    #pragma unroll
    for (int k = 0; k < H8; ++k) r |= s_z8[tid*H8 + k];
    z9[b*C3 + tid] = (float)r;                  // z9[t=0][b][c]
  }
}

// ---- F1: gated exact fallback — per-batch repair of t=0 state + full
//      t=1..29 recurrence. Returns immediately when alive2==0 (measured). ----
__global__ __launch_bounds__(NTHR) void f1_fallback(
    const float* __restrict__ x,  const float* __restrict__ w1,
    const float* __restrict__ w2, const float* __restrict__ w3,
    const unsigned char* __restrict__ z3g, const unsigned char* __restrict__ z5g,
    float* v1, unsigned char* m1, unsigned char* z2,
    float* __restrict__ z9, const int* alive2)
{
  if (*alive2 == 0) return;
  const int b = blockIdx.x, tid = threadIdx.x;
  __shared__ float s_w1[C1*25];
  __shared__ unsigned char s_z3[Z3PB];
  __shared__ float s_v2[N_V2PB];
  __shared__ unsigned char s_m2[N_V2PB], s_z5[N_V2PB];
  __shared__ float s_v3[C3*H8];
  __shared__ unsigned char s_m3[C3*H8], s_z8[C3*H8];

  for (int i = tid; i < C1*25; i += NTHR) s_w1[i] = w1[i];
  float* v1b = v1 + (size_t)b*N1PB;
  unsigned char* m1b = m1 + (size_t)b*N1PB;
  unsigned char* z2b = z2 + (size_t)b*N1PB;
  __syncthreads();

  // repair t=0: conv1 state
  const float* x0 = x + (size_t)b*H_IN*W_IN;
  for (int idx = tid; idx < N1PB; idx += NTHR) {
    int xw = idx % W1O; int r = idx / W1O;
    int y  = r % H1;    int c = r / H1;
    const float* xp = x0 + (size_t)y*W_IN + xw;
    const float* wp = s_w1 + c*25;
    float s = 0.f;
    #pragma unroll
    for (int i = 0; i < 5; ++i)
      #pragma unroll
      for (int j = 0; j < 5; ++j) s = fmaf(xp[i*W_IN + j], wp[i*5 + j], s);
    bool z = (s >= 10.0f);
    v1b[idx] = z ? 0.f : s;
    m1b[idx] = z ? 0 : 1;
  }
  // repair t=0: conv2 state (from K1's z3)
  for (int i = tid; i < Z3PB; i += NTHR) s_z3[i] = z3g[(size_t)b*Z3PB + i];
  __syncthreads();
  for (int o = tid; o < N_V2PB; o += NTHR) {
    int c  = o / (H2*W2O);
    int r  = o - c*(H2*W2O);
    int oy = r / W2O, ox = r - (r/W2O)*W2O;
    const float* wb = w2 + (size_t)c*C1*256;
    float s = 0.f;
    for (int ci = 0; ci < C1; ++ci)
      for (int i = 0; i < 16; ++i) {
        const unsigned char* ip = s_z3 + (ci*H3 + oy + i)*W3 + ox;
        const float* wp = wb + ci*256 + i*16;
        #pragma unroll
        for (int j = 0; j < 16; ++j) s = fmaf((float)ip[j], wp[j], s);
      }
    bool z = (s >= 60.0f);
    s_v2[o] = z ? 0.f : s;
    s_m2[o] = z ? 0 : 1;
  }
  // repair t=0: conv3 state (from K2's z5)
  for (int i = tid; i < N_V2PB; i += NTHR) s_z5[i] = z5g[(size_t)b*N_V2PB + i];
  __syncthreads();
  for (int o = tid; o < C3*H8; o += NTHR) {
    int c3 = o >> 3, oy = o & 7;
    float s = 0.f;
    for (int ci = 0; ci < C2; ++ci) {
      const unsigned char* zp = s_z5 + ci*H2*W2O;
      const float* wp = w3 + ((size_t)c3*C2 + ci)*25;
      #pragma unroll
      for (int i = 0; i < 5; ++i) {
        const unsigned char* r0 = zp + (2*(oy + i))*W2O;
        const unsigned char* r1 = r0 + W2O;
        #pragma unroll
        for (int j = 0; j < 5; ++j) {
          unsigned char zv = r0[2*j] | r0[2*j+1] | r1[2*j] | r1[2*j+1];
          s = fmaf((float)zv, wp[i*5 + j], s);
        }
      }
    }
    bool z = (s >= 2.0f);
    s_v3[o] = z ? 0.f : s;
    s_m3[o] = z ? 0 : 1;
  }
  __syncthreads();

  // exact recurrence t = 1..29 for this batch
  for (int t = 1; t < T_STEPS; ++t) {
    const float* xt = x + ((size_t)t*BATCH + b)*H_IN*W_IN;
    for (int idx = tid; idx < N1PB; idx += NTHR) {        // conv1+IAF
      int xw = idx % W1O; int r = idx / W1O;
      int y  = r % H1;    int c = r / H1;
      const float* xp = xt + (size_t)y*W_IN + xw;
      const float* wp = s_w1 + c*25;
      float s = 0.f;
      #pragma unroll
      for (int i = 0; i < 5; ++i)
        #pragma unroll
        for (int j = 0; j < 5; ++j) s = fmaf(xp[i*W_IN + j], wp[i*5 + j], s);
      float v = v1b[idx] + s;
      bool  z = (v >= 10.0f);
      v1b[idx] = z ? 0.f : v;
      unsigned char m = m1b[idx];
      z2b[idx] = (z && m) ? 1 : 0;
      m1b[idx] = (m && !z) ? 1 : 0;
    }
    __syncthreads();
    for (int i = tid; i < Z3PB; i += NTHR) {              // pool1 = OR
      int px = i % W3; int r = i / W3;
      int py = r % H3; int c = r / H3;
      const unsigned char* p = z2b + ((size_t)c*H1 + py*6)*W1O + px*6;
      unsigned char rr = 0;
      #pragma unroll
      for (int ii = 0; ii < 7; ++ii)
        #pragma unroll
        for (int jj = 0; jj < 7; ++jj) rr |= p[ii*W1O + jj];
      s_z3[i] = rr;
    }
    __syncthreads();
    for (int o = tid; o < N_V2PB; o += NTHR) {            // conv2+IAF
      int c  = o / (H2*W2O);
      int r  = o - c*(H2*W2O);
      int oy = r / W2O, ox = r - (r/W2O)*W2O;
      const float* wb = w2 + (size_t)c*C1*256;
      float s = 0.f;
      for (int ci = 0; ci < C1; ++ci)
        for (int i = 0; i < 16; ++i) {
          const unsigned char* ip = s_z3 + (ci*H3 + oy + i)*W3 + ox;
          const float* wp = wb + ci*256 + i*16;
          #pragma unroll
          for (int j = 0; j < 16; ++j) s = fmaf((float)ip[j], wp[j], s);
        }
      float v = s_v2[o] + s;
      bool  z = (v >= 60.0f);
      s_v2[o] = z ? 0.f : v;
      unsigned char m = s_m2[o];
      s_z5[o] = (z && m) ? 1 : 0;
      s_m2[o] = (m && !z) ? 1 : 0;
    }
    __syncthreads();
    for (int o = tid; o < C3*H8; o += NTHR) {             // conv3+IAF (pool folded)
      int c3 = o >> 3, oy = o & 7;
      float s = 0.f;
      for (int ci = 0; ci < C2; ++ci) {
        const unsigned char* zp = s_z5 + ci*H2*W2O;
        const float* wp = w3 + ((size_t)c3*C2 + ci)*25;
        #pragma unroll
        for (int i = 0; i < 5; ++i) {
          const unsigned char* r0 = zp + (2*(oy + i))*W2O;
          const unsigned char* r1 = r0 + W2O;
          #pragma unroll
          for (int j = 0; j < 5; ++j) {
            unsigned char zv = r0[2*j] | r0[2*j+1] | r1[2*j] | r1[2*j+1];
            s = fmaf((float)zv, wp[i*5 + j], s);
          }
        }
      }
      float v = s_v3[o] + s;
      bool  z = (v >= 2.0f);
      s_v3[o] = z ? 0.f : v;
      unsigned char m = s_m3[o];
      s_z8[o] = (z && m) ? 1 : 0;
      s_m3[o] = (m && !z) ? 1 : 0;
    }
    __syncthreads();
    if (tid < C3) {                                       // z9[t][b][c]
      unsigned char r = 0;
      #pragma unroll
      for (int k = 0; k < H8; ++k) r |= s_z8[tid*H8 + k];
      z9[(size_t)t*N_FEAT + b*C3 + tid] = (float)r;
    }
    __syncthreads();
  }
}

// ---- F2: readout head for all 30 steps (closed-form tail when dead) +
//      weight-clip outputs ----
__global__ __launch_bounds__(NTHR) void f2_head(
    const float* __restrict__ z9,
    const float* __restrict__ fc1_w, const float* __restrict__ fc1_b,
    const float* __restrict__ out_w, const float* __restrict__ out_b,
    const float* __restrict__ w1,    const float* __restrict__ w2,
    float* __restrict__ out, const int* alive2)
{
  const int tid = threadIdx.x;
  const int gid = blockIdx.x*NTHR + tid;
  const int gsz = gridDim.x*NTHR;
  float* out_w1 = out + T_STEPS*N_FEAT;
  float* out_w2 = out_w1 + C1*25;
  for (int i = gid; i < C1*25;     i += gsz) out_w1[i] = fminf(fmaxf(w1[i], 0.f), 1.f);
  for (int i = gid; i < C2*C1*256; i += gsz) out_w2[i] = fminf(fmaxf(w2[i], 0.f), 1.f);
  if (blockIdx.x != 0) return;

  __shared__ float s_feat[N_FEAT], s_h[64], s_li[10], s_lv[10];
  __shared__ float s_tail[T_STEPS*10];
  if (tid < 10) { s_li[tid] = 0.f; s_lv[tid] = 0.f; }
  __syncthreads();
  const bool alive = (*alive2 != 0);
  const int tmax = alive ? T_STEPS : 1;

  for (int t = 0; t < tmax; ++t) {
    for (int i = tid; i < N_FEAT; i += NTHR) s_feat[i] = z9[(size_t)t*N_FEAT + i];
    __syncthreads();
    {
      int o = tid >> 2, q = tid & 3;            // 4 lanes per fc1 output
      if (o < 50) {
        const float* wr = fc1_w + (size_t)o*N_FEAT + q*80;
        const float* fr = s_feat + q*80;
        float s = 0.f;
        for (int j = 0; j < 80; ++j) s = fmaf(fr[j], wr[j], s);
        s += __shfl_xor(s, 1, 64);
        s += __shfl_xor(s, 2, 64);
        if (q == 0) s_h[o] = fmaxf(s + fc1_b[o], 0.f);
      }
    }
    __syncthreads();
    if (tid < 10) {
      float idec = s_li[tid]*0.8f;              // 1 - dt*tau_syn_inv
      float vnew = s_lv[tid] + 0.1f*(idec - s_lv[tid]);
      float acc = idec + out_b[tid];
      for (int k = 0; k < 50; ++k) acc = fmaf(s_h[k], out_w[tid*50 + k], acc);
      s_li[tid] = acc;
      s_lv[tid] = vnew;
    }
    __syncthreads();
    float* vt = out + (size_t)t*N_FEAT;
    for (int i = tid; i < N_FEAT; i += NTHR) vt[i] = s_lv[i % 10];
    __syncthreads();
  }

  if (!alive) {                                 // closed-form tail t=1..29
    if (tid < 50) s_h[tid] = fmaxf(fc1_b[tid], 0.f);
    __syncthreads();
    if (tid < 10) {
      float c = out_b[tid];
      for (int k = 0; k < 50; ++k) c = fmaf(s_h[k], out_w[tid*50 + k], c);
      float li = s_li[tid], lv = s_lv[tid];
      for (int tt = 1; tt < T_STEPS; ++tt) {
        float idec = li*0.8f;
        lv = lv + 0.1f*(idec - lv);
        li = idec + c;
        s_tail[(tt - 1)*10 + tid] = lv;
      }
    }
    __syncthreads();
    int nrem = (T_STEPS - 1)*N_FEAT;
    float* vt = out + (size_t)N_FEAT;
    for (int i = tid; i < nrem; i += NTHR)
      vt[i] = s_tail[(i/N_FEAT)*10 + (i % 10)];
  }
}

extern "C" void kernel_launch(void* const* d_in, const int* in_sizes, int n_in,
                              void* d_out, int out_size, void* d_ws, size_t ws_size,
                              hipStream_t stream) {
  const float* x      = (const float*)d_in[0];
  const float* w1     = (const float*)d_in[1];
  const float* w2     = (const float*)d_in[2];
  const float* w3     = (const float*)d_in[3];
  const float* fc1_w  = (const float*)d_in[4];
  const float* fc1_b  = (const float*)d_in[5];
  const float* out_w  = (const float*)d_in[6];
  const float* out_b  = (const float*)d_in[7];
  float* out = (float*)d_out;   // [volts 30*320 | w1 100 | w2 20480]

  char* p = (char*)d_ws;
  float* v1 = (float*)p;                  p += (size_t)N_V1*4;
  float* z9 = (float*)p;                  p += (size_t)T_STEPS*N_FEAT*4;
  int* alive2 = (int*)p;                  p += 4;
  p += 60;                                // pad to 64B
  unsigned char* m1 = (unsigned char*)p;  p += N_V1;
  unsigned char* z2 = (unsigned char*)p;  p += N_V1;
  unsigned char* z3 = (unsigned char*)p;  p += N_Z3;
  unsigned char* z5 = (unsigned char*)p;  p += N_V2;

  k1_conv1pool<<<975, NTHR, 0, stream>>>(x, w1, z3, alive2);     // N_POOL*8 threads
  k2_conv2<<<2400, NTHR, 0, stream>>>(z3, w2, z5, alive2);       // 1 item/thread
  k3_conv3<<<BATCH, NTHR, 0, stream>>>(z5, w3, z9);
  f1_fallback<<<BATCH, NTHR, 0, stream>>>(x, w1, w2, w3, z3, z5,
                                          v1, m1, z2, z9, alive2);
  f2_head<<<64, NTHR, 0, stream>>>(z9, fc1_w, fc1_b, out_w, out_b,
                                   w1, w2, out, alive2);
}

// Round 8
// 127.866 us; speedup vs baseline: 1.2909x; 1.2909x over previous
//
#include <hip/hip_runtime.h>

// ConvNet_STDP — 5 regular kernels, stream-ordered, NO cooperative launch.
//
// Verified (rounds 1-7, absmax 0.0):
//  * STDP provably inert -> weight outputs are clip(w_init, 0, 1).
//  * Network dies at t=0 for this input -> fast path computes only step 0;
//    gated per-batch fallback (f1) is exact for any input.
//  * R6 lesson: k2 inner loop of ds_read_u8 -> 85us. R7 lesson: predicated
//    GLOBAL weight loads -> VGPR 132, occupancy 10%, 148us (worse).
//  * R8 fix: block=(b,c); w2[c] (4KB) + packed 25-bit row masks in LDS;
//    weight reads are lane-UNIFORM (LDS broadcast, conflict-free);
//    zero global traffic in the tap loop. Accumulation order unchanged
//    (ci->i->j, single accumulator) -> bitwise identical.

#define T_STEPS 30
#define BATCH   32
#define H_IN    240
#define W_IN    160
#define C1      4
#define H1      236
#define W1O     156
#define H3      39
#define W3      25
#define C2      20
#define H2      24
#define W2O     10
#define C3      10
#define H8      8

#define N1PB   (C1*H1*W1O)         // 147,264 per-batch conv1 positions
#define N_V1   (BATCH*N1PB)        // 4,712,448
#define N_V2PB (C2*H2*W2O)         // 4,800
#define N_V2   (BATCH*N_V2PB)      // 153,600
#define Z3PB   (C1*H3*W3)          // 3,900
#define N_Z3   (BATCH*Z3PB)        // 124,800
#define N_POOL (BATCH*H3*W3)       // 31,200
#define N_FEAT (BATCH*C3)          // 320

#define NTHR 256

// ---- K1: fused conv1+pool1 (t=0, stateless) -> z3; init alive2 ----
__global__ __launch_bounds__(NTHR) void k1_conv1pool(
    const float* __restrict__ x, const float* __restrict__ w1,
    unsigned char* __restrict__ z3, int* alive2)
{
  __shared__ float s_w1[C1*25];
  for (int i = threadIdx.x; i < C1*25; i += NTHR) s_w1[i] = w1[i];
  __syncthreads();
  int it = blockIdx.x*NTHR + threadIdx.x;
  if (it == 0) *alive2 = N_V2;
  int o = it >> 3, q = it & 7;
  int px = o % W3; int tt = o / W3;
  int py = tt % H3; int b = tt / H3;
  unsigned mask = 0;
  if (q < 7) {
    const float* xb = x + (size_t)b*H_IN*W_IN;
    int ybase = py*6 + q;                       // this lane's window row
    float acc[C1][7];
    #pragma unroll
    for (int c = 0; c < C1; ++c)
      #pragma unroll
      for (int wx = 0; wx < 7; ++wx) acc[c][wx] = 0.f;
    #pragma unroll
    for (int i = 0; i < 5; ++i) {
      const float* xp = xb + (size_t)(ybase + i)*W_IN + px*6;
      float xr[11];
      #pragma unroll
      for (int k = 0; k < 11; ++k) xr[k] = xp[k];
      #pragma unroll
      for (int j = 0; j < 5; ++j) {
        float w0 = s_w1[ 0 + i*5 + j];
        float w1v = s_w1[25 + i*5 + j];
        float w2v = s_w1[50 + i*5 + j];
        float w3v = s_w1[75 + i*5 + j];
        #pragma unroll
        for (int wx = 0; wx < 7; ++wx) {
          float xv = xr[wx + j];
          acc[0][wx] = fmaf(xv, w0,  acc[0][wx]);
          acc[1][wx] = fmaf(xv, w1v, acc[1][wx]);
          acc[2][wx] = fmaf(xv, w2v, acc[2][wx]);
          acc[3][wx] = fmaf(xv, w3v, acc[3][wx]);
        }
      }
    }
    #pragma unroll
    for (int c = 0; c < C1; ++c)
      #pragma unroll
      for (int wx = 0; wx < 7; ++wx)
        mask |= (acc[c][wx] >= 10.f) ? (1u << c) : 0u;
  }
  mask |= __shfl_xor(mask, 1, 64);
  mask |= __shfl_xor(mask, 2, 64);
  mask |= __shfl_xor(mask, 4, 64);
  if (q == 0 && o < N_POOL) {
    unsigned char* zp = z3 + (size_t)b*Z3PB + py*W3 + px;
    zp[0]        =  mask       & 1;
    zp[H3*W3]    = (mask >> 1) & 1;
    zp[2*H3*W3]  = (mask >> 2) & 1;
    zp[3*H3*W3]  = (mask >> 3) & 1;
  }
}

// ---- K2: conv2 + IAF(60) (t=0: v=s, m=1) -> z5; alive2 -= fired ----
// Block = (b, c). w2[c] (1024 floats) + 156 packed row masks in LDS.
// Thread = one output; weight reads lane-uniform (LDS broadcast).
__global__ __launch_bounds__(NTHR) void k2_conv2(
    const unsigned char* __restrict__ z3, const float* __restrict__ w2,
    unsigned char* __restrict__ z5, int* alive2)
{
  __shared__ unsigned s_mask[C1*H3];            // 156 packed rows
  __shared__ float    s_w[C1*256];              // 4KB: w2[c]
  const int b = blockIdx.x & 31;                // grid = 640 = 20c x 32b
  const int c = blockIdx.x >> 5;
  const int tid = threadIdx.x;
  ((float4*)s_w)[tid] = ((const float4*)(w2 + (size_t)c*C1*256))[tid];
  if (tid < C1*H3) {
    const unsigned char* rp = z3 + (size_t)b*Z3PB + tid*W3;
    unsigned m = 0;
    #pragma unroll
    for (int k = 0; k < W3; ++k) m |= (rp[k] ? 1u : 0u) << k;
    s_mask[tid] = m;
  }
  __syncthreads();
  int nf = 0;
  if (tid < H2*W2O) {
    int oy = tid / W2O, ox = tid - (tid/W2O)*W2O;
    float s = 0.f;
    for (int ci = 0; ci < C1; ++ci) {
      #pragma unroll
      for (int i = 0; i < 16; ++i) {
        unsigned m = s_mask[ci*H3 + oy + i] >> ox;   // window row bits 0..15
        const float* wp = s_w + ci*256 + i*16;       // lane-uniform address
        #pragma unroll
        for (int j = 0; j < 16; ++j)
          s += (m & (1u << j)) ? wp[j] : 0.f;        // == fmaf(z,w,s) bitwise
      }
    }
    unsigned char sp = (s >= 60.0f) ? 1 : 0;
    z5[b*N_V2PB + c*(H2*W2O) + tid] = sp;
    nf = sp;
  }
  #pragma unroll
  for (int o2 = 1; o2 < 64; o2 <<= 1) nf += __shfl_xor(nf, o2, 64);
  if ((tid & 63) == 0 && nf) atomicSub(alive2, nf);
}

// ---- K3: conv3 (pool2 folded) + IAF(2) (t=0) -> z9[0]. One block/batch ----
__global__ __launch_bounds__(NTHR) void k3_conv3(
    const unsigned char* __restrict__ z5, const float* __restrict__ w3,
    float* __restrict__ z9)
{
  const int b = blockIdx.x, tid = threadIdx.x;
  __shared__ unsigned int s_z5w[N_V2PB/4];
  __shared__ unsigned char s_z8[C3*H8];
  const unsigned int* zsrc = (const unsigned int*)(z5 + (size_t)b*N_V2PB);
  for (int i = tid; i < N_V2PB/4; i += NTHR) s_z5w[i] = zsrc[i];
  __syncthreads();
  const unsigned char* sz = (const unsigned char*)s_z5w;
  for (int it = tid; it < C3*H8*4; it += NTHR) {
    int o = it >> 2, g = it & 3;                // 5-channel group per lane
    int c3 = o >> 3, oy = o & 7;
    float s = 0.f;
    for (int ci = g*5; ci < g*5 + 5; ++ci) {
      const unsigned char* zp = sz + ci*H2*W2O;
      const float* wp = w3 + ((size_t)c3*C2 + ci)*25;
      #pragma unroll
      for (int i = 0; i < 5; ++i) {
        const unsigned char* r0 = zp + (2*(oy + i))*W2O;
        const unsigned char* r1 = r0 + W2O;
        #pragma unroll
        for (int j = 0; j < 5; ++j) {
          unsigned char zv = r0[2*j] | r0[2*j+1] | r1[2*j] | r1[2*j+1];
          s = fmaf((float)zv, wp[i*5 + j], s);
        }
      }
    }
    s += __shfl_xor(s, 1, 64);
    s += __shfl_xor(s, 2, 64);
    if (g == 0) s_z8[o] = (s >= 2.0f) ? 1 : 0;
  }
  __syncthreads();
  if (tid < C3) {
    unsigned char r = 0;
    #pragma unroll
    for (int k = 0; k < H8; ++k) r |= s_z8[tid*H8 + k];
    z9[b*C3 + tid] = (float)r;                  // z9[t=0][b][c]
  }
}

// ---- F1: gated exact fallback — per-batch repair of t=0 state + full
//      t=1..29 recurrence. Returns immediately when alive2==0 (measured). ----
__global__ __launch_bounds__(NTHR) void f1_fallback(
    const float* __restrict__ x,  const float* __restrict__ w1,
    const float* __restrict__ w2, const float* __restrict__ w3,
    const unsigned char* __restrict__ z3g, const unsigned char* __restrict__ z5g,
    float* v1, unsigned char* m1, unsigned char* z2,
    float* __restrict__ z9, const int* alive2)
{
  if (*alive2 == 0) return;
  const int b = blockIdx.x, tid = threadIdx.x;
  __shared__ float s_w1[C1*25];
  __shared__ unsigned char s_z3[Z3PB];
  __shared__ float s_v2[N_V2PB];
  __shared__ unsigned char s_m2[N_V2PB], s_z5[N_V2PB];
  __shared__ float s_v3[C3*H8];
  __shared__ unsigned char s_m3[C3*H8], s_z8[C3*H8];

  for (int i = tid; i < C1*25; i += NTHR) s_w1[i] = w1[i];
  float* v1b = v1 + (size_t)b*N1PB;
  unsigned char* m1b = m1 + (size_t)b*N1PB;
  unsigned char* z2b = z2 + (size_t)b*N1PB;
  __syncthreads();

  // repair t=0: conv1 state
  const float* x0 = x + (size_t)b*H_IN*W_IN;
  for (int idx = tid; idx < N1PB; idx += NTHR) {
    int xw = idx % W1O; int r = idx / W1O;
    int y  = r % H1;    int c = r / H1;
    const float* xp = x0 + (size_t)y*W_IN + xw;
    const float* wp = s_w1 + c*25;
    float s = 0.f;
    #pragma unroll
    for (int i = 0; i < 5; ++i)
      #pragma unroll
      for (int j = 0; j < 5; ++j) s = fmaf(xp[i*W_IN + j], wp[i*5 + j], s);
    bool z = (s >= 10.0f);
    v1b[idx] = z ? 0.f : s;
    m1b[idx] = z ? 0 : 1;
  }
  // repair t=0: conv2 state (from K1's z3)
  for (int i = tid; i < Z3PB; i += NTHR) s_z3[i] = z3g[(size_t)b*Z3PB + i];
  __syncthreads();
  for (int o = tid; o < N_V2PB; o += NTHR) {
    int c  = o / (H2*W2O);
    int r  = o - c*(H2*W2O);
    int oy = r / W2O, ox = r - (r/W2O)*W2O;
    const float* wb = w2 + (size_t)c*C1*256;
    float s = 0.f;
    for (int ci = 0; ci < C1; ++ci)
      for (int i = 0; i < 16; ++i) {
        const unsigned char* ip = s_z3 + (ci*H3 + oy + i)*W3 + ox;
        const float* wp = wb + ci*256 + i*16;
        #pragma unroll
        for (int j = 0; j < 16; ++j) s = fmaf((float)ip[j], wp[j], s);
      }
    bool z = (s >= 60.0f);
    s_v2[o] = z ? 0.f : s;
    s_m2[o] = z ? 0 : 1;
  }
  // repair t=0: conv3 state (from K2's z5)
  for (int i = tid; i < N_V2PB; i += NTHR) s_z5[i] = z5g[(size_t)b*N_V2PB + i];
  __syncthreads();
  for (int o = tid; o < C3*H8; o += NTHR) {
    int c3 = o >> 3, oy = o & 7;
    float s = 0.f;
    for (int ci = 0; ci < C2; ++ci) {
      const unsigned char* zp = s_z5 + ci*H2*W2O;
      const float* wp = w3 + ((size_t)c3*C2 + ci)*25;
      #pragma unroll
      for (int i = 0; i < 5; ++i) {
        const unsigned char* r0 = zp + (2*(oy + i))*W2O;
        const unsigned char* r1 = r0 + W2O;
        #pragma unroll
        for (int j = 0; j < 5; ++j) {
          unsigned char zv = r0[2*j] | r0[2*j+1] | r1[2*j] | r1[2*j+1];
          s = fmaf((float)zv, wp[i*5 + j], s);
        }
      }
    }
    bool z = (s >= 2.0f);
    s_v3[o] = z ? 0.f : s;
    s_m3[o] = z ? 0 : 1;
  }
  __syncthreads();

  // exact recurrence t = 1..29 for this batch
  for (int t = 1; t < T_STEPS; ++t) {
    const float* xt = x + ((size_t)t*BATCH + b)*H_IN*W_IN;
    for (int idx = tid; idx < N1PB; idx += NTHR) {        // conv1+IAF
      int xw = idx % W1O; int r = idx / W1O;
      int y  = r % H1;    int c = r / H1;
      const float* xp = xt + (size_t)y*W_IN + xw;
      const float* wp = s_w1 + c*25;
      float s = 0.f;
      #pragma unroll
      for (int i = 0; i < 5; ++i)
        #pragma unroll
        for (int j = 0; j < 5; ++j) s = fmaf(xp[i*W_IN + j], wp[i*5 + j], s);
      float v = v1b[idx] + s;
      bool  z = (v >= 10.0f);
      v1b[idx] = z ? 0.f : v;
      unsigned char m = m1b[idx];
      z2b[idx] = (z && m) ? 1 : 0;
      m1b[idx] = (m && !z) ? 1 : 0;
    }
    __syncthreads();
    for (int i = tid; i < Z3PB; i += NTHR) {              // pool1 = OR
      int px = i % W3; int r = i / W3;
      int py = r % H3; int c = r / H3;
      const unsigned char* p = z2b + ((size_t)c*H1 + py*6)*W1O + px*6;
      unsigned char rr = 0;
      #pragma unroll
      for (int ii = 0; ii < 7; ++ii)
        #pragma unroll
        for (int jj = 0; jj < 7; ++jj) rr |= p[ii*W1O + jj];
      s_z3[i] = rr;
    }
    __syncthreads();
    for (int o = tid; o < N_V2PB; o += NTHR) {            // conv2+IAF
      int c  = o / (H2*W2O);
      int r  = o - c*(H2*W2O);
      int oy = r / W2O, ox = r - (r/W2O)*W2O;
      const float* wb = w2 + (size_t)c*C1*256;
      float s = 0.f;
      for (int ci = 0; ci < C1; ++ci)
        for (int i = 0; i < 16; ++i) {
          const unsigned char* ip = s_z3 + (ci*H3 + oy + i)*W3 + ox;
          const float* wp = wb + ci*256 + i*16;
          #pragma unroll
          for (int j = 0; j < 16; ++j) s = fmaf((float)ip[j], wp[j], s);
        }
      float v = s_v2[o] + s;
      bool  z = (v >= 60.0f);
      s_v2[o] = z ? 0.f : v;
      unsigned char m = s_m2[o];
      s_z5[o] = (z && m) ? 1 : 0;
      s_m2[o] = (m && !z) ? 1 : 0;
    }
    __syncthreads();
    for (int o = tid; o < C3*H8; o += NTHR) {             // conv3+IAF (pool folded)
      int c3 = o >> 3, oy = o & 7;
      float s = 0.f;
      for (int ci = 0; ci < C2; ++ci) {
        const unsigned char* zp = s_z5 + ci*H2*W2O;
        const float* wp = w3 + ((size_t)c3*C2 + ci)*25;
        #pragma unroll
        for (int i = 0; i < 5; ++i) {
          const unsigned char* r0 = zp + (2*(oy + i))*W2O;
          const unsigned char* r1 = r0 + W2O;
          #pragma unroll
          for (int j = 0; j < 5; ++j) {
            unsigned char zv = r0[2*j] | r0[2*j+1] | r1[2*j] | r1[2*j+1];
            s = fmaf((float)zv, wp[i*5 + j], s);
          }
        }
      }
      float v = s_v3[o] + s;
      bool  z = (v >= 2.0f);
      s_v3[o] = z ? 0.f : v;
      unsigned char m = s_m3[o];
      s_z8[o] = (z && m) ? 1 : 0;
      s_m3[o] = (m && !z) ? 1 : 0;
    }
    __syncthreads();
    if (tid < C3) {                                       // z9[t][b][c]
      unsigned char r = 0;
      #pragma unroll
      for (int k = 0; k < H8; ++k) r |= s_z8[tid*H8 + k];
      z9[(size_t)t*N_FEAT + b*C3 + tid] = (float)r;
    }
    __syncthreads();
  }
}

// ---- F2: readout head for all 30 steps (closed-form tail when dead) +
//      weight-clip outputs ----
__global__ __launch_bounds__(NTHR) void f2_head(
    const float* __restrict__ z9,
    const float* __restrict__ fc1_w, const float* __restrict__ fc1_b,
    const float* __restrict__ out_w, const float* __restrict__ out_b,
    const float* __restrict__ w1,    const float* __restrict__ w2,
    float* __restrict__ out, const int* alive2)
{
  const int tid = threadIdx.x;
  const int gid = blockIdx.x*NTHR + tid;
  const int gsz = gridDim.x*NTHR;
  float* out_w1 = out + T_STEPS*N_FEAT;
  float* out_w2 = out_w1 + C1*25;
  for (int i = gid; i < C1*25;     i += gsz) out_w1[i] = fminf(fmaxf(w1[i], 0.f), 1.f);
  for (int i = gid; i < C2*C1*256; i += gsz) out_w2[i] = fminf(fmaxf(w2[i], 0.f), 1.f);
  if (blockIdx.x != 0) return;

  __shared__ float s_feat[N_FEAT], s_h[64], s_li[10], s_lv[10];
  __shared__ float s_tail[T_STEPS*10];
  if (tid < 10) { s_li[tid] = 0.f; s_lv[tid] = 0.f; }
  __syncthreads();
  const bool alive = (*alive2 != 0);
  const int tmax = alive ? T_STEPS : 1;

  for (int t = 0; t < tmax; ++t) {
    for (int i = tid; i < N_FEAT; i += NTHR) s_feat[i] = z9[(size_t)t*N_FEAT + i];
    __syncthreads();
    {
      int o = tid >> 2, q = tid & 3;            // 4 lanes per fc1 output
      if (o < 50) {
        const float* wr = fc1_w + (size_t)o*N_FEAT + q*80;
        const float* fr = s_feat + q*80;
        float s = 0.f;
        for (int j = 0; j < 80; ++j) s = fmaf(fr[j], wr[j], s);
        s += __shfl_xor(s, 1, 64);
        s += __shfl_xor(s, 2, 64);
        if (q == 0) s_h[o] = fmaxf(s + fc1_b[o], 0.f);
      }
    }
    __syncthreads();
    if (tid < 10) {
      float idec = s_li[tid]*0.8f;              // 1 - dt*tau_syn_inv
      float vnew = s_lv[tid] + 0.1f*(idec - s_lv[tid]);
      float acc = idec + out_b[tid];
      for (int k = 0; k < 50; ++k) acc = fmaf(s_h[k], out_w[tid*50 + k], acc);
      s_li[tid] = acc;
      s_lv[tid] = vnew;
    }
    __syncthreads();
    float* vt = out + (size_t)t*N_FEAT;
    for (int i = tid; i < N_FEAT; i += NTHR) vt[i] = s_lv[i % 10];
    __syncthreads();
  }

  if (!alive) {                                 // closed-form tail t=1..29
    if (tid < 50) s_h[tid] = fmaxf(fc1_b[tid], 0.f);
    __syncthreads();
    if (tid < 10) {
      float c = out_b[tid];
      for (int k = 0; k < 50; ++k) c = fmaf(s_h[k], out_w[tid*50 + k], c);
      float li = s_li[tid], lv = s_lv[tid];
      for (int tt = 1; tt < T_STEPS; ++tt) {
        float idec = li*0.8f;
        lv = lv + 0.1f*(idec - lv);
        li = idec + c;
        s_tail[(tt - 1)*10 + tid] = lv;
      }
    }
    __syncthreads();
    int nrem = (T_STEPS - 1)*N_FEAT;
    float* vt = out + (size_t)N_FEAT;
    for (int i = tid; i < nrem; i += NTHR)
      vt[i] = s_tail[(i/N_FEAT)*10 + (i % 10)];
  }
}

extern "C" void kernel_launch(void* const* d_in, const int* in_sizes, int n_in,
                              void* d_out, int out_size, void* d_ws, size_t ws_size,
                              hipStream_t stream) {
  const float* x      = (const float*)d_in[0];
  const float* w1     = (const float*)d_in[1];
  const float* w2     = (const float*)d_in[2];
  const float* w3     = (const float*)d_in[3];
  const float* fc1_w  = (const float*)d_in[4];
  const float* fc1_b  = (const float*)d_in[5];
  const float* out_w  = (const float*)d_in[6];
  const float* out_b  = (const float*)d_in[7];
  float* out = (float*)d_out;   // [volts 30*320 | w1 100 | w2 20480]

  char* p = (char*)d_ws;
  float* v1 = (float*)p;                  p += (size_t)N_V1*4;
  float* z9 = (float*)p;                  p += (size_t)T_STEPS*N_FEAT*4;
  int* alive2 = (int*)p;                  p += 4;
  p += 60;                                // pad to 64B
  unsigned char* m1 = (unsigned char*)p;  p += N_V1;
  unsigned char* z2 = (unsigned char*)p;  p += N_V1;
  unsigned char* z3 = (unsigned char*)p;  p += N_Z3;
  unsigned char* z5 = (unsigned char*)p;  p += N_V2;

  k1_conv1pool<<<975, NTHR, 0, stream>>>(x, w1, z3, alive2);     // N_POOL*8 threads
  k2_conv2<<<C2*BATCH, NTHR, 0, stream>>>(z3, w2, z5, alive2);   // 640: (c,b) blocks
  k3_conv3<<<BATCH, NTHR, 0, stream>>>(z5, w3, z9);
  f1_fallback<<<BATCH, NTHR, 0, stream>>>(x, w1, w2, w3, z3, z5,
                                          v1, m1, z2, z9, alive2);
  f2_head<<<64, NTHR, 0, stream>>>(z9, fc1_w, fc1_b, out_w, out_b,
                                   w1, w2, out, alive2);
}

// Round 9
// 110.921 us; speedup vs baseline: 1.4881x; 1.1528x over previous
//
#include <hip/hip_runtime.h>

// ConvNet_STDP — 5 regular kernels, stream-ordered, NO cooperative launch.
//
// Verified (rounds 1-8, absmax 0.0):
//  * STDP provably inert -> weight outputs are clip(w_init, 0, 1).
//  * Network dies at t=0 for this input -> fast path computes only step 0;
//    gated per-batch fallback (f1) is exact for any input.
//  * R6/R7/R8 lesson: k2 stuck at 85-148us regardless of compute changes.
//    Shared trait: ~2.5k same-address device atomicSubs (~43ns each,
//    serialized across 8 XCDs; kernel end-of-pipe waits for drain).
//  * R9 fix: no atomics. k2 block-reduces "any non-fired output" and does
//    at most ONE plain store of alive_flag=1 (dead case: zero stores).
//    k1 inits the flag; f1/f2 gate on it. Conv/IAF math byte-identical.

#define T_STEPS 30
#define BATCH   32
#define H_IN    240
#define W_IN    160
#define C1      4
#define H1      236
#define W1O     156
#define H3      39
#define W3      25
#define C2      20
#define H2      24
#define W2O     10
#define C3      10
#define H8      8

#define N1PB   (C1*H1*W1O)         // 147,264 per-batch conv1 positions
#define N_V1   (BATCH*N1PB)        // 4,712,448
#define N_V2PB (C2*H2*W2O)         // 4,800
#define N_V2   (BATCH*N_V2PB)      // 153,600
#define Z3PB   (C1*H3*W3)          // 3,900
#define N_Z3   (BATCH*Z3PB)        // 124,800
#define N_POOL (BATCH*H3*W3)       // 31,200
#define N_FEAT (BATCH*C3)          // 320

#define NTHR 256

// ---- K1: fused conv1+pool1 (t=0, stateless) -> z3; init alive_flag ----
__global__ __launch_bounds__(NTHR) void k1_conv1pool(
    const float* __restrict__ x, const float* __restrict__ w1,
    unsigned char* __restrict__ z3, int* alive_flag)
{
  __shared__ float s_w1[C1*25];
  for (int i = threadIdx.x; i < C1*25; i += NTHR) s_w1[i] = w1[i];
  __syncthreads();
  int it = blockIdx.x*NTHR + threadIdx.x;
  if (it == 0) *alive_flag = 0;
  int o = it >> 3, q = it & 7;
  int px = o % W3; int tt = o / W3;
  int py = tt % H3; int b = tt / H3;
  unsigned mask = 0;
  if (q < 7) {
    const float* xb = x + (size_t)b*H_IN*W_IN;
    int ybase = py*6 + q;                       // this lane's window row
    float acc[C1][7];
    #pragma unroll
    for (int c = 0; c < C1; ++c)
      #pragma unroll
      for (int wx = 0; wx < 7; ++wx) acc[c][wx] = 0.f;
    #pragma unroll
    for (int i = 0; i < 5; ++i) {
      const float* xp = xb + (size_t)(ybase + i)*W_IN + px*6;
      float xr[11];
      #pragma unroll
      for (int k = 0; k < 11; ++k) xr[k] = xp[k];
      #pragma unroll
      for (int j = 0; j < 5; ++j) {
        float w0 = s_w1[ 0 + i*5 + j];
        float w1v = s_w1[25 + i*5 + j];
        float w2v = s_w1[50 + i*5 + j];
        float w3v = s_w1[75 + i*5 + j];
        #pragma unroll
        for (int wx = 0; wx < 7; ++wx) {
          float xv = xr[wx + j];
          acc[0][wx] = fmaf(xv, w0,  acc[0][wx]);
          acc[1][wx] = fmaf(xv, w1v, acc[1][wx]);
          acc[2][wx] = fmaf(xv, w2v, acc[2][wx]);
          acc[3][wx] = fmaf(xv, w3v, acc[3][wx]);
        }
      }
    }
    #pragma unroll
    for (int c = 0; c < C1; ++c)
      #pragma unroll
      for (int wx = 0; wx < 7; ++wx)
        mask |= (acc[c][wx] >= 10.f) ? (1u << c) : 0u;
  }
  mask |= __shfl_xor(mask, 1, 64);
  mask |= __shfl_xor(mask, 2, 64);
  mask |= __shfl_xor(mask, 4, 64);
  if (q == 0 && o < N_POOL) {
    unsigned char* zp = z3 + (size_t)b*Z3PB + py*W3 + px;
    zp[0]        =  mask       & 1;
    zp[H3*W3]    = (mask >> 1) & 1;
    zp[2*H3*W3]  = (mask >> 2) & 1;
    zp[3*H3*W3]  = (mask >> 3) & 1;
  }
}

// ---- K2: conv2 + IAF(60) (t=0: v=s, m=1) -> z5; alive_flag (no atomics) ----
// Block = (b, c). w2[c] (1024 floats) + 156 packed row masks in LDS.
// Thread = one output; weight reads lane-uniform (LDS broadcast).
__global__ __launch_bounds__(NTHR) void k2_conv2(
    const unsigned char* __restrict__ z3, const float* __restrict__ w2,
    unsigned char* __restrict__ z5, int* alive_flag)
{
  __shared__ unsigned s_mask[C1*H3];            // 156 packed rows
  __shared__ float    s_w[C1*256];              // 4KB: w2[c]
  __shared__ int      s_any[NTHR/64];
  const int b = blockIdx.x & 31;                // grid = 640 = 20c x 32b
  const int c = blockIdx.x >> 5;
  const int tid = threadIdx.x;
  ((float4*)s_w)[tid] = ((const float4*)(w2 + (size_t)c*C1*256))[tid];
  if (tid < C1*H3) {
    const unsigned char* rp = z3 + (size_t)b*Z3PB + tid*W3;
    unsigned m = 0;
    #pragma unroll
    for (int k = 0; k < W3; ++k) m |= (rp[k] ? 1u : 0u) << k;
    s_mask[tid] = m;
  }
  __syncthreads();
  int surv = 0;                                 // this output survives (didn't fire)
  if (tid < H2*W2O) {
    int oy = tid / W2O, ox = tid - (tid/W2O)*W2O;
    float s = 0.f;
    for (int ci = 0; ci < C1; ++ci) {
      #pragma unroll
      for (int i = 0; i < 16; ++i) {
        unsigned m = s_mask[ci*H3 + oy + i] >> ox;   // window row bits 0..15
        const float* wp = s_w + ci*256 + i*16;       // lane-uniform address
        #pragma unroll
        for (int j = 0; j < 16; ++j)
          s += (m & (1u << j)) ? wp[j] : 0.f;        // == fmaf(z,w,s) bitwise
      }
    }
    unsigned char sp = (s >= 60.0f) ? 1 : 0;
    z5[b*N_V2PB + c*(H2*W2O) + tid] = sp;
    surv = (sp == 0);
  }
  unsigned long long bal = __ballot(surv != 0);
  if ((tid & 63) == 0) s_any[tid >> 6] = (bal != 0ULL);
  __syncthreads();
  if (tid == 0 && (s_any[0] | s_any[1] | s_any[2] | s_any[3]))
    *alive_flag = 1;                            // plain store; dead case: no store
}

// ---- K3: conv3 (pool2 folded) + IAF(2) (t=0) -> z9[0]. One block/batch ----
__global__ __launch_bounds__(NTHR) void k3_conv3(
    const unsigned char* __restrict__ z5, const float* __restrict__ w3,
    float* __restrict__ z9)
{
  const int b = blockIdx.x, tid = threadIdx.x;
  __shared__ unsigned int s_z5w[N_V2PB/4];
  __shared__ unsigned char s_z8[C3*H8];
  const unsigned int* zsrc = (const unsigned int*)(z5 + (size_t)b*N_V2PB);
  for (int i = tid; i < N_V2PB/4; i += NTHR) s_z5w[i] = zsrc[i];
  __syncthreads();
  const unsigned char* sz = (const unsigned char*)s_z5w;
  for (int it = tid; it < C3*H8*4; it += NTHR) {
    int o = it >> 2, g = it & 3;                // 5-channel group per lane
    int c3 = o >> 3, oy = o & 7;
    float s = 0.f;
    for (int ci = g*5; ci < g*5 + 5; ++ci) {
      const unsigned char* zp = sz + ci*H2*W2O;
      const float* wp = w3 + ((size_t)c3*C2 + ci)*25;
      #pragma unroll
      for (int i = 0; i < 5; ++i) {
        const unsigned char* r0 = zp + (2*(oy + i))*W2O;
        const unsigned char* r1 = r0 + W2O;
        #pragma unroll
        for (int j = 0; j < 5; ++j) {
          unsigned char zv = r0[2*j] | r0[2*j+1] | r1[2*j] | r1[2*j+1];
          s = fmaf((float)zv, wp[i*5 + j], s);
        }
      }
    }
    s += __shfl_xor(s, 1, 64);
    s += __shfl_xor(s, 2, 64);
    if (g == 0) s_z8[o] = (s >= 2.0f) ? 1 : 0;
  }
  __syncthreads();
  if (tid < C3) {
    unsigned char r = 0;
    #pragma unroll
    for (int k = 0; k < H8; ++k) r |= s_z8[tid*H8 + k];
    z9[b*C3 + tid] = (float)r;                  // z9[t=0][b][c]
  }
}

// ---- F1: gated exact fallback — per-batch repair of t=0 state + full
//      t=1..29 recurrence. Returns immediately when alive_flag==0 (measured). ----
__global__ __launch_bounds__(NTHR) void f1_fallback(
    const float* __restrict__ x,  const float* __restrict__ w1,
    const float* __restrict__ w2, const float* __restrict__ w3,
    const unsigned char* __restrict__ z3g, const unsigned char* __restrict__ z5g,
    float* v1, unsigned char* m1, unsigned char* z2,
    float* __restrict__ z9, const int* alive_flag)
{
  if (*alive_flag == 0) return;
  const int b = blockIdx.x, tid = threadIdx.x;
  __shared__ float s_w1[C1*25];
  __shared__ unsigned char s_z3[Z3PB];
  __shared__ float s_v2[N_V2PB];
  __shared__ unsigned char s_m2[N_V2PB], s_z5[N_V2PB];
  __shared__ float s_v3[C3*H8];
  __shared__ unsigned char s_m3[C3*H8], s_z8[C3*H8];

  for (int i = tid; i < C1*25; i += NTHR) s_w1[i] = w1[i];
  float* v1b = v1 + (size_t)b*N1PB;
  unsigned char* m1b = m1 + (size_t)b*N1PB;
  unsigned char* z2b = z2 + (size_t)b*N1PB;
  __syncthreads();

  // repair t=0: conv1 state
  const float* x0 = x + (size_t)b*H_IN*W_IN;
  for (int idx = tid; idx < N1PB; idx += NTHR) {
    int xw = idx % W1O; int r = idx / W1O;
    int y  = r % H1;    int c = r / H1;
    const float* xp = x0 + (size_t)y*W_IN + xw;
    const float* wp = s_w1 + c*25;
    float s = 0.f;
    #pragma unroll
    for (int i = 0; i < 5; ++i)
      #pragma unroll
      for (int j = 0; j < 5; ++j) s = fmaf(xp[i*W_IN + j], wp[i*5 + j], s);
    bool z = (s >= 10.0f);
    v1b[idx] = z ? 0.f : s;
    m1b[idx] = z ? 0 : 1;
  }
  // repair t=0: conv2 state (from K1's z3)
  for (int i = tid; i < Z3PB; i += NTHR) s_z3[i] = z3g[(size_t)b*Z3PB + i];
  __syncthreads();
  for (int o = tid; o < N_V2PB; o += NTHR) {
    int c  = o / (H2*W2O);
    int r  = o - c*(H2*W2O);
    int oy = r / W2O, ox = r - (r/W2O)*W2O;
    const float* wb = w2 + (size_t)c*C1*256;
    float s = 0.f;
    for (int ci = 0; ci < C1; ++ci)
      for (int i = 0; i < 16; ++i) {
        const unsigned char* ip = s_z3 + (ci*H3 + oy + i)*W3 + ox;
        const float* wp = wb + ci*256 + i*16;
        #pragma unroll
        for (int j = 0; j < 16; ++j) s = fmaf((float)ip[j], wp[j], s);
      }
    bool z = (s >= 60.0f);
    s_v2[o] = z ? 0.f : s;
    s_m2[o] = z ? 0 : 1;
  }
  // repair t=0: conv3 state (from K2's z5)
  for (int i = tid; i < N_V2PB; i += NTHR) s_z5[i] = z5g[(size_t)b*N_V2PB + i];
  __syncthreads();
  for (int o = tid; o < C3*H8; o += NTHR) {
    int c3 = o >> 3, oy = o & 7;
    float s = 0.f;
    for (int ci = 0; ci < C2; ++ci) {
      const unsigned char* zp = s_z5 + ci*H2*W2O;
      const float* wp = w3 + ((size_t)c3*C2 + ci)*25;
      #pragma unroll
      for (int i = 0; i < 5; ++i) {
        const unsigned char* r0 = zp + (2*(oy + i))*W2O;
        const unsigned char* r1 = r0 + W2O;
        #pragma unroll
        for (int j = 0; j < 5; ++j) {
          unsigned char zv = r0[2*j] | r0[2*j+1] | r1[2*j] | r1[2*j+1];
          s = fmaf((float)zv, wp[i*5 + j], s);
        }
      }
    }
    bool z = (s >= 2.0f);
    s_v3[o] = z ? 0.f : s;
    s_m3[o] = z ? 0 : 1;
  }
  __syncthreads();

  // exact recurrence t = 1..29 for this batch
  for (int t = 1; t < T_STEPS; ++t) {
    const float* xt = x + ((size_t)t*BATCH + b)*H_IN*W_IN;
    for (int idx = tid; idx < N1PB; idx += NTHR) {        // conv1+IAF
      int xw = idx % W1O; int r = idx / W1O;
      int y  = r % H1;    int c = r / H1;
      const float* xp = xt + (size_t)y*W_IN + xw;
      const float* wp = s_w1 + c*25;
      float s = 0.f;
      #pragma unroll
      for (int i = 0; i < 5; ++i)
        #pragma unroll
        for (int j = 0; j < 5; ++j) s = fmaf(xp[i*W_IN + j], wp[i*5 + j], s);
      float v = v1b[idx] + s;
      bool  z = (v >= 10.0f);
      v1b[idx] = z ? 0.f : v;
      unsigned char m = m1b[idx];
      z2b[idx] = (z && m) ? 1 : 0;
      m1b[idx] = (m && !z) ? 1 : 0;
    }
    __syncthreads();
    for (int i = tid; i < Z3PB; i += NTHR) {              // pool1 = OR
      int px = i % W3; int r = i / W3;
      int py = r % H3; int c = r / H3;
      const unsigned char* p = z2b + ((size_t)c*H1 + py*6)*W1O + px*6;
      unsigned char rr = 0;
      #pragma unroll
      for (int ii = 0; ii < 7; ++ii)
        #pragma unroll
        for (int jj = 0; jj < 7; ++jj) rr |= p[ii*W1O + jj];
      s_z3[i] = rr;
    }
    __syncthreads();
    for (int o = tid; o < N_V2PB; o += NTHR) {            // conv2+IAF
      int c  = o / (H2*W2O);
      int r  = o - c*(H2*W2O);
      int oy = r / W2O, ox = r - (r/W2O)*W2O;
      const float* wb = w2 + (size_t)c*C1*256;
      float s = 0.f;
      for (int ci = 0; ci < C1; ++ci)
        for (int i = 0; i < 16; ++i) {
          const unsigned char* ip = s_z3 + (ci*H3 + oy + i)*W3 + ox;
          const float* wp = wb + ci*256 + i*16;
          #pragma unroll
          for (int j = 0; j < 16; ++j) s = fmaf((float)ip[j], wp[j], s);
        }
      float v = s_v2[o] + s;
      bool  z = (v >= 60.0f);
      s_v2[o] = z ? 0.f : v;
      unsigned char m = s_m2[o];
      s_z5[o] = (z && m) ? 1 : 0;
      s_m2[o] = (m && !z) ? 1 : 0;
    }
    __syncthreads();
    for (int o = tid; o < C3*H8; o += NTHR) {             // conv3+IAF (pool folded)
      int c3 = o >> 3, oy = o & 7;
      float s = 0.f;
      for (int ci = 0; ci < C2; ++ci) {
        const unsigned char* zp = s_z5 + ci*H2*W2O;
        const float* wp = w3 + ((size_t)c3*C2 + ci)*25;
        #pragma unroll
        for (int i = 0; i < 5; ++i) {
          const unsigned char* r0 = zp + (2*(oy + i))*W2O;
          const unsigned char* r1 = r0 + W2O;
          #pragma unroll
          for (int j = 0; j < 5; ++j) {
            unsigned char zv = r0[2*j] | r0[2*j+1] | r1[2*j] | r1[2*j+1];
            s = fmaf((float)zv, wp[i*5 + j], s);
          }
        }
      }
      float v = s_v3[o] + s;
      bool  z = (v >= 2.0f);
      s_v3[o] = z ? 0.f : v;
      unsigned char m = s_m3[o];
      s_z8[o] = (z && m) ? 1 : 0;
      s_m3[o] = (m && !z) ? 1 : 0;
    }
    __syncthreads();
    if (tid < C3) {                                       // z9[t][b][c]
      unsigned char r = 0;
      #pragma unroll
      for (int k = 0; k < H8; ++k) r |= s_z8[tid*H8 + k];
      z9[(size_t)t*N_FEAT + b*C3 + tid] = (float)r;
    }
    __syncthreads();
  }
}

// ---- F2: readout head for all 30 steps (closed-form tail when dead) +
//      weight-clip outputs ----
__global__ __launch_bounds__(NTHR) void f2_head(
    const float* __restrict__ z9,
    const float* __restrict__ fc1_w, const float* __restrict__ fc1_b,
    const float* __restrict__ out_w, const float* __restrict__ out_b,
    const float* __restrict__ w1,    const float* __restrict__ w2,
    float* __restrict__ out, const int* alive_flag)
{
  const int tid = threadIdx.x;
  const int gid = blockIdx.x*NTHR + tid;
  const int gsz = gridDim.x*NTHR;
  float* out_w1 = out + T_STEPS*N_FEAT;
  float* out_w2 = out_w1 + C1*25;
  for (int i = gid; i < C1*25;     i += gsz) out_w1[i] = fminf(fmaxf(w1[i], 0.f), 1.f);
  for (int i = gid; i < C2*C1*256; i += gsz) out_w2[i] = fminf(fmaxf(w2[i], 0.f), 1.f);
  if (blockIdx.x != 0) return;

  __shared__ float s_feat[N_FEAT], s_h[64], s_li[10], s_lv[10];
  __shared__ float s_tail[T_STEPS*10];
  if (tid < 10) { s_li[tid] = 0.f; s_lv[tid] = 0.f; }
  __syncthreads();
  const bool alive = (*alive_flag != 0);
  const int tmax = alive ? T_STEPS : 1;

  for (int t = 0; t < tmax; ++t) {
    for (int i = tid; i < N_FEAT; i += NTHR) s_feat[i] = z9[(size_t)t*N_FEAT + i];
    __syncthreads();
    {
      int o = tid >> 2, q = tid & 3;            // 4 lanes per fc1 output
      if (o < 50) {
        const float* wr = fc1_w + (size_t)o*N_FEAT + q*80;
        const float* fr = s_feat + q*80;
        float s = 0.f;
        for (int j = 0; j < 80; ++j) s = fmaf(fr[j], wr[j], s);
        s += __shfl_xor(s, 1, 64);
        s += __shfl_xor(s, 2, 64);
        if (q == 0) s_h[o] = fmaxf(s + fc1_b[o], 0.f);
      }
    }
    __syncthreads();
    if (tid < 10) {
      float idec = s_li[tid]*0.8f;              // 1 - dt*tau_syn_inv
      float vnew = s_lv[tid] + 0.1f*(idec - s_lv[tid]);
      float acc = idec + out_b[tid];
      for (int k = 0; k < 50; ++k) acc = fmaf(s_h[k], out_w[tid*50 + k], acc);
      s_li[tid] = acc;
      s_lv[tid] = vnew;
    }
    __syncthreads();
    float* vt = out + (size_t)t*N_FEAT;
    for (int i = tid; i < N_FEAT; i += NTHR) vt[i] = s_lv[i % 10];
    __syncthreads();
  }

  if (!alive) {                                 // closed-form tail t=1..29
    if (tid < 50) s_h[tid] = fmaxf(fc1_b[tid], 0.f);
    __syncthreads();
    if (tid < 10) {
      float c = out_b[tid];
      for (int k = 0; k < 50; ++k) c = fmaf(s_h[k], out_w[tid*50 + k], c);
      float li = s_li[tid], lv = s_lv[tid];
      for (int tt = 1; tt < T_STEPS; ++tt) {
        float idec = li*0.8f;
        lv = lv + 0.1f*(idec - lv);
        li = idec + c;
        s_tail[(tt - 1)*10 + tid] = lv;
      }
    }
    __syncthreads();
    int nrem = (T_STEPS - 1)*N_FEAT;
    float* vt = out + (size_t)N_FEAT;
    for (int i = tid; i < nrem; i += NTHR)
      vt[i] = s_tail[(i/N_FEAT)*10 + (i % 10)];
  }
}

extern "C" void kernel_launch(void* const* d_in, const int* in_sizes, int n_in,
                              void* d_out, int out_size, void* d_ws, size_t ws_size,
                              hipStream_t stream) {
  const float* x      = (const float*)d_in[0];
  const float* w1     = (const float*)d_in[1];
  const float* w2     = (const float*)d_in[2];
  const float* w3     = (const float*)d_in[3];
  const float* fc1_w  = (const float*)d_in[4];
  const float* fc1_b  = (const float*)d_in[5];
  const float* out_w  = (const float*)d_in[6];
  const float* out_b  = (const float*)d_in[7];
  float* out = (float*)d_out;   // [volts 30*320 | w1 100 | w2 20480]

  char* p = (char*)d_ws;
  float* v1 = (float*)p;                  p += (size_t)N_V1*4;
  float* z9 = (float*)p;                  p += (size_t)T_STEPS*N_FEAT*4;
  int* alive_flag = (int*)p;              p += 4;
  p += 60;                                // pad to 64B
  unsigned char* m1 = (unsigned char*)p;  p += N_V1;
  unsigned char* z2 = (unsigned char*)p;  p += N_V1;
  unsigned char* z3 = (unsigned char*)p;  p += N_Z3;
  unsigned char* z5 = (unsigned char*)p;  p += N_V2;

  k1_conv1pool<<<975, NTHR, 0, stream>>>(x, w1, z3, alive_flag);   // N_POOL*8 threads
  k2_conv2<<<C2*BATCH, NTHR, 0, stream>>>(z3, w2, z5, alive_flag); // 640: (c,b) blocks
  k3_conv3<<<BATCH, NTHR, 0, stream>>>(z5, w3, z9);
  f1_fallback<<<BATCH, NTHR, 0, stream>>>(x, w1, w2, w3, z3, z5,
                                          v1, m1, z2, z9, alive_flag);
  f2_head<<<64, NTHR, 0, stream>>>(z9, fc1_w, fc1_b, out_w, out_b,
                                   w1, w2, out, alive_flag);
}

// Round 10
// 55.383 us; speedup vs baseline: 2.9803x; 2.0028x over previous
//
#include <hip/hip_runtime.h>

// ConvNet_STDP — 5 regular kernels, stream-ordered, NO cooperative launch.
//
// Verified (rounds 1-9, absmax 0.0):
//  * STDP provably inert -> weight outputs are clip(w_init, 0, 1).
//  * Network dies at t=0 for this input -> fast path computes only step 0;
//    gated per-batch fallback (f1) is exact for any input.
//  * k2 history: 85-148us across THREE bodies (R6 LDS byte reads, R7 global
//    loads, R8/R9 uniform LDS broadcast). Invariant = ~1k DS/VMEM
//    instructions per wave (~6cyc each, 4 useful bytes each).
//  * R10 fix: weights live in REGISTERS (lane l holds w[c][l>>4][l&15][0..16)),
//    one per-lane ds_read of the mask serves 10 outputs; 1024 taps/output
//    spread over 64 lanes + shfl tree reduce. DS insts/wave 1088 -> ~8.
//  * Tree reduce reorders FP sums; all spike margins are O(100) vs O(ulp),
//    and f1 is now fully self-contained (recomputes z3/z5/z9[0] from x
//    exactly when alive), so only alive_flag depends on k2 rounding.

#define T_STEPS 30
#define BATCH   32
#define H_IN    240
#define W_IN    160
#define C1      4
#define H1      236
#define W1O     156
#define H3      39
#define W3      25
#define C2      20
#define H2      24
#define W2O     10
#define C3      10
#define H8      8

#define N1PB   (C1*H1*W1O)         // 147,264 per-batch conv1 positions
#define N_V1   (BATCH*N1PB)        // 4,712,448
#define N_V2PB (C2*H2*W2O)         // 4,800
#define N_V2   (BATCH*N_V2PB)      // 153,600
#define Z3PB   (C1*H3*W3)          // 3,900
#define N_Z3   (BATCH*Z3PB)        // 124,800
#define N_POOL (BATCH*H3*W3)       // 31,200
#define N_FEAT (BATCH*C3)          // 320

#define NTHR 256

// ---- K1: fused conv1+pool1 (t=0, stateless) -> z3; init alive_flag ----
__global__ __launch_bounds__(NTHR) void k1_conv1pool(
    const float* __restrict__ x, const float* __restrict__ w1,
    unsigned char* __restrict__ z3, int* alive_flag)
{
  __shared__ float s_w1[C1*25];
  for (int i = threadIdx.x; i < C1*25; i += NTHR) s_w1[i] = w1[i];
  __syncthreads();
  int it = blockIdx.x*NTHR + threadIdx.x;
  if (it == 0) *alive_flag = 0;
  int o = it >> 3, q = it & 7;
  int px = o % W3; int tt = o / W3;
  int py = tt % H3; int b = tt / H3;
  unsigned mask = 0;
  if (q < 7) {
    const float* xb = x + (size_t)b*H_IN*W_IN;
    int ybase = py*6 + q;                       // this lane's window row
    float acc[C1][7];
    #pragma unroll
    for (int c = 0; c < C1; ++c)
      #pragma unroll
      for (int wx = 0; wx < 7; ++wx) acc[c][wx] = 0.f;
    #pragma unroll
    for (int i = 0; i < 5; ++i) {
      const float* xp = xb + (size_t)(ybase + i)*W_IN + px*6;
      float xr[11];
      #pragma unroll
      for (int k = 0; k < 11; ++k) xr[k] = xp[k];
      #pragma unroll
      for (int j = 0; j < 5; ++j) {
        float w0 = s_w1[ 0 + i*5 + j];
        float w1v = s_w1[25 + i*5 + j];
        float w2v = s_w1[50 + i*5 + j];
        float w3v = s_w1[75 + i*5 + j];
        #pragma unroll
        for (int wx = 0; wx < 7; ++wx) {
          float xv = xr[wx + j];
          acc[0][wx] = fmaf(xv, w0,  acc[0][wx]);
          acc[1][wx] = fmaf(xv, w1v, acc[1][wx]);
          acc[2][wx] = fmaf(xv, w2v, acc[2][wx]);
          acc[3][wx] = fmaf(xv, w3v, acc[3][wx]);
        }
      }
    }
    #pragma unroll
    for (int c = 0; c < C1; ++c)
      #pragma unroll
      for (int wx = 0; wx < 7; ++wx)
        mask |= (acc[c][wx] >= 10.f) ? (1u << c) : 0u;
  }
  mask |= __shfl_xor(mask, 1, 64);
  mask |= __shfl_xor(mask, 2, 64);
  mask |= __shfl_xor(mask, 4, 64);
  if (q == 0 && o < N_POOL) {
    unsigned char* zp = z3 + (size_t)b*Z3PB + py*W3 + px;
    zp[0]        =  mask       & 1;
    zp[H3*W3]    = (mask >> 1) & 1;
    zp[2*H3*W3]  = (mask >> 2) & 1;
    zp[3*H3*W3]  = (mask >> 3) & 1;
  }
}

// ---- K2: conv2 + IAF(60) (t=0) -> z5; alive_flag. Weight-in-register. ----
// Block=(b,c), 4 waves x 60 outputs. Lane l holds w[c][l>>4][l&15][0..16).
// Per oy: ONE per-lane ds_read of the packed mask serves 10 outputs.
__global__ __launch_bounds__(NTHR) void k2_conv2(
    const unsigned char* __restrict__ z3, const float* __restrict__ w2,
    unsigned char* __restrict__ z5, int* alive_flag)
{
  __shared__ unsigned s_mask[C1*H3];            // 156 packed rows
  __shared__ int s_any[4];
  const int b = blockIdx.x & 31;                // grid = 640 = 20c x 32b
  const int c = blockIdx.x >> 5;
  const int tid = threadIdx.x;
  const int lane = tid & 63;
  const int wv = tid >> 6;
  if (tid < C1*H3) {                            // pack row tid (25 bytes -> 25 bits)
    const unsigned char* rp = z3 + (size_t)b*Z3PB + tid*W3;
    unsigned m = 0;
    #pragma unroll
    for (int k = 0; k < W3; ++k) m |= (rp[k] ? 1u : 0u) << k;
    s_mask[tid] = m;
  }
  float wreg[16];                               // 4 coalesced float4 loads
  {
    const float4* wp = (const float4*)(w2 + (size_t)c*C1*256 + lane*16);
    #pragma unroll
    for (int k = 0; k < 4; ++k) {
      float4 v = wp[k];
      wreg[4*k+0] = v.x; wreg[4*k+1] = v.y; wreg[4*k+2] = v.z; wreg[4*k+3] = v.w;
    }
  }
  __syncthreads();
  const int mrow = (lane >> 4)*H3 + (lane & 15);   // ci*H3 + i (lane-fixed)
  int surv = 0;
  for (int oy = wv*6; oy < wv*6 + 6; ++oy) {
    unsigned mw = s_mask[mrow + oy];            // 1 DS read / 10 outputs
    #pragma unroll
    for (int ox = 0; ox < 10; ++ox) {
      unsigned mm = mw >> ox;
      float s = 0.f;
      #pragma unroll
      for (int j = 0; j < 16; ++j)
        s += (mm & (1u << j)) ? wreg[j] : 0.f;  // register taps, 64 lanes
      #pragma unroll
      for (int d = 1; d < 64; d <<= 1)          // tree reduce (see header note)
        s += __shfl_xor(s, d, 64);
      if (lane == 0) {
        unsigned char sp = (s >= 60.0f) ? 1 : 0;
        z5[b*N_V2PB + c*(H2*W2O) + oy*W2O + ox] = sp;
        surv |= (sp == 0);
      }
    }
  }
  if (lane == 0) s_any[wv] = surv;
  __syncthreads();
  if (tid == 0 && (s_any[0] | s_any[1] | s_any[2] | s_any[3]))
    *alive_flag = 1;                            // plain store; dead case: no store
}

// ---- K3: conv3 (pool2 folded) + IAF(2) (t=0) -> z9[0]. One block/batch ----
__global__ __launch_bounds__(NTHR) void k3_conv3(
    const unsigned char* __restrict__ z5, const float* __restrict__ w3,
    float* __restrict__ z9)
{
  const int b = blockIdx.x, tid = threadIdx.x;
  __shared__ unsigned int s_z5w[N_V2PB/4];
  __shared__ unsigned char s_z8[C3*H8];
  const unsigned int* zsrc = (const unsigned int*)(z5 + (size_t)b*N_V2PB);
  for (int i = tid; i < N_V2PB/4; i += NTHR) s_z5w[i] = zsrc[i];
  __syncthreads();
  const unsigned char* sz = (const unsigned char*)s_z5w;
  for (int it = tid; it < C3*H8*4; it += NTHR) {
    int o = it >> 2, g = it & 3;                // 5-channel group per lane
    int c3 = o >> 3, oy = o & 7;
    float s = 0.f;
    for (int ci = g*5; ci < g*5 + 5; ++ci) {
      const unsigned char* zp = sz + ci*H2*W2O;
      const float* wp = w3 + ((size_t)c3*C2 + ci)*25;
      #pragma unroll
      for (int i = 0; i < 5; ++i) {
        const unsigned char* r0 = zp + (2*(oy + i))*W2O;
        const unsigned char* r1 = r0 + W2O;
        #pragma unroll
        for (int j = 0; j < 5; ++j) {
          unsigned char zv = r0[2*j] | r0[2*j+1] | r1[2*j] | r1[2*j+1];
          s = fmaf((float)zv, wp[i*5 + j], s);
        }
      }
    }
    s += __shfl_xor(s, 1, 64);
    s += __shfl_xor(s, 2, 64);
    if (g == 0) s_z8[o] = (s >= 2.0f) ? 1 : 0;
  }
  __syncthreads();
  if (tid < C3) {
    unsigned char r = 0;
    #pragma unroll
    for (int k = 0; k < H8; ++k) r |= s_z8[tid*H8 + k];
    z9[b*C3 + tid] = (float)r;                  // z9[t=0][b][c]
  }
}

// ---- F1: gated exact fallback — SELF-CONTAINED per-batch recompute of t=0
//      (conv1/pool/conv2/conv3/z9[0], exact reference order) + t=1..29
//      recurrence. Returns immediately when alive_flag==0 (measured case). ----
__global__ __launch_bounds__(NTHR) void f1_fallback(
    const float* __restrict__ x,  const float* __restrict__ w1,
    const float* __restrict__ w2, const float* __restrict__ w3,
    float* v1, unsigned char* m1, unsigned char* z2,
    float* __restrict__ z9, const int* alive_flag)
{
  if (*alive_flag == 0) return;
  const int b = blockIdx.x, tid = threadIdx.x;
  __shared__ float s_w1[C1*25];
  __shared__ unsigned char s_z3[Z3PB];
  __shared__ float s_v2[N_V2PB];
  __shared__ unsigned char s_m2[N_V2PB], s_z5[N_V2PB];
  __shared__ float s_v3[C3*H8];
  __shared__ unsigned char s_m3[C3*H8], s_z8[C3*H8];

  for (int i = tid; i < C1*25; i += NTHR) s_w1[i] = w1[i];
  float* v1b = v1 + (size_t)b*N1PB;
  unsigned char* m1b = m1 + (size_t)b*N1PB;
  unsigned char* z2b = z2 + (size_t)b*N1PB;
  __syncthreads();

  // t=0: conv1 state (exact order). Fired at t=0 <=> m1b==0.
  const float* x0 = x + (size_t)b*H_IN*W_IN;
  for (int idx = tid; idx < N1PB; idx += NTHR) {
    int xw = idx % W1O; int r = idx / W1O;
    int y  = r % H1;    int c = r / H1;
    const float* xp = x0 + (size_t)y*W_IN + xw;
    const float* wp = s_w1 + c*25;
    float s = 0.f;
    #pragma unroll
    for (int i = 0; i < 5; ++i)
      #pragma unroll
      for (int j = 0; j < 5; ++j) s = fmaf(xp[i*W_IN + j], wp[i*5 + j], s);
    bool z = (s >= 10.0f);
    v1b[idx] = z ? 0.f : s;
    m1b[idx] = z ? 0 : 1;
  }
  __syncthreads();
  // t=0: pool1 from m1b (spike <=> mask cleared at t=0)
  for (int i = tid; i < Z3PB; i += NTHR) {
    int px = i % W3; int r = i / W3;
    int py = r % H3; int cc = r / H3;
    const unsigned char* p = m1b + ((size_t)cc*H1 + py*6)*W1O + px*6;
    unsigned char rr = 0;
    #pragma unroll
    for (int ii = 0; ii < 7; ++ii)
      #pragma unroll
      for (int jj = 0; jj < 7; ++jj) rr |= (p[ii*W1O + jj] == 0) ? 1 : 0;
    s_z3[i] = rr;
  }
  __syncthreads();
  // t=0: conv2 state + exact z5
  for (int o = tid; o < N_V2PB; o += NTHR) {
    int c  = o / (H2*W2O);
    int r  = o - c*(H2*W2O);
    int oy = r / W2O, ox = r - (r/W2O)*W2O;
    const float* wb = w2 + (size_t)c*C1*256;
    float s = 0.f;
    for (int ci = 0; ci < C1; ++ci)
      for (int i = 0; i < 16; ++i) {
        const unsigned char* ip = s_z3 + (ci*H3 + oy + i)*W3 + ox;
        const float* wp = wb + ci*256 + i*16;
        #pragma unroll
        for (int j = 0; j < 16; ++j) s = fmaf((float)ip[j], wp[j], s);
      }
    bool z = (s >= 60.0f);
    s_v2[o] = z ? 0.f : s;
    s_m2[o] = z ? 0 : 1;
    s_z5[o] = z ? 1 : 0;                        // t=0: m=1 -> spike = z
  }
  __syncthreads();
  // t=0: conv3 state + z8 (from exact z5)
  for (int o = tid; o < C3*H8; o += NTHR) {
    int c3 = o >> 3, oy = o & 7;
    float s = 0.f;
    for (int ci = 0; ci < C2; ++ci) {
      const unsigned char* zp = s_z5 + ci*H2*W2O;
      const float* wp = w3 + ((size_t)c3*C2 + ci)*25;
      #pragma unroll
      for (int i = 0; i < 5; ++i) {
        const unsigned char* r0 = zp + (2*(oy + i))*W2O;
        const unsigned char* r1 = r0 + W2O;
        #pragma unroll
        for (int j = 0; j < 5; ++j) {
          unsigned char zv = r0[2*j] | r0[2*j+1] | r1[2*j] | r1[2*j+1];
          s = fmaf((float)zv, wp[i*5 + j], s);
        }
      }
    }
    bool z = (s >= 2.0f);
    s_v3[o] = z ? 0.f : s;
    s_m3[o] = z ? 0 : 1;
    s_z8[o] = z ? 1 : 0;                        // t=0: m=1
  }
  __syncthreads();
  if (tid < C3) {                               // exact z9[0] overwrites k3's
    unsigned char r = 0;
    #pragma unroll
    for (int k = 0; k < H8; ++k) r |= s_z8[tid*H8 + k];
    z9[b*C3 + tid] = (float)r;
  }
  __syncthreads();

  // exact recurrence t = 1..29 for this batch
  for (int t = 1; t < T_STEPS; ++t) {
    const float* xt = x + ((size_t)t*BATCH + b)*H_IN*W_IN;
    for (int idx = tid; idx < N1PB; idx += NTHR) {        // conv1+IAF
      int xw = idx % W1O; int r = idx / W1O;
      int y  = r % H1;    int c = r / H1;
      const float* xp = xt + (size_t)y*W_IN + xw;
      const float* wp = s_w1 + c*25;
      float s = 0.f;
      #pragma unroll
      for (int i = 0; i < 5; ++i)
        #pragma unroll
        for (int j = 0; j < 5; ++j) s = fmaf(xp[i*W_IN + j], wp[i*5 + j], s);
      float v = v1b[idx] + s;
      bool  z = (v >= 10.0f);
      v1b[idx] = z ? 0.f : v;
      unsigned char m = m1b[idx];
      z2b[idx] = (z && m) ? 1 : 0;
      m1b[idx] = (m && !z) ? 1 : 0;
    }
    __syncthreads();
    for (int i = tid; i < Z3PB; i += NTHR) {              // pool1 = OR
      int px = i % W3; int r = i / W3;
      int py = r % H3; int c = r / H3;
      const unsigned char* p = z2b + ((size_t)c*H1 + py*6)*W1O + px*6;
      unsigned char rr = 0;
      #pragma unroll
      for (int ii = 0; ii < 7; ++ii)
        #pragma unroll
        for (int jj = 0; jj < 7; ++jj) rr |= p[ii*W1O + jj];
      s_z3[i] = rr;
    }
    __syncthreads();
    for (int o = tid; o < N_V2PB; o += NTHR) {            // conv2+IAF
      int c  = o / (H2*W2O);
      int r  = o - c*(H2*W2O);
      int oy = r / W2O, ox = r - (r/W2O)*W2O;
      const float* wb = w2 + (size_t)c*C1*256;
      float s = 0.f;
      for (int ci = 0; ci < C1; ++ci)
        for (int i = 0; i < 16; ++i) {
          const unsigned char* ip = s_z3 + (ci*H3 + oy + i)*W3 + ox;
          const float* wp = wb + ci*256 + i*16;
          #pragma unroll
          for (int j = 0; j < 16; ++j) s = fmaf((float)ip[j], wp[j], s);
        }
      float v = s_v2[o] + s;
      bool  z = (v >= 60.0f);
      s_v2[o] = z ? 0.f : v;
      unsigned char m = s_m2[o];
      s_z5[o] = (z && m) ? 1 : 0;
      s_m2[o] = (m && !z) ? 1 : 0;
    }
    __syncthreads();
    for (int o = tid; o < C3*H8; o += NTHR) {             // conv3+IAF (pool folded)
      int c3 = o >> 3, oy = o & 7;
      float s = 0.f;
      for (int ci = 0; ci < C2; ++ci) {
        const unsigned char* zp = s_z5 + ci*H2*W2O;
        const float* wp = w3 + ((size_t)c3*C2 + ci)*25;
        #pragma unroll
        for (int i = 0; i < 5; ++i) {
          const unsigned char* r0 = zp + (2*(oy + i))*W2O;
          const unsigned char* r1 = r0 + W2O;
          #pragma unroll
          for (int j = 0; j < 5; ++j) {
            unsigned char zv = r0[2*j] | r0[2*j+1] | r1[2*j] | r1[2*j+1];
            s = fmaf((float)zv, wp[i*5 + j], s);
          }
        }
      }
      float v = s_v3[o] + s;
      bool  z = (v >= 2.0f);
      s_v3[o] = z ? 0.f : v;
      unsigned char m = s_m3[o];
      s_z8[o] = (z && m) ? 1 : 0;
      s_m3[o] = (m && !z) ? 1 : 0;
    }
    __syncthreads();
    if (tid < C3) {                                       // z9[t][b][c]
      unsigned char r = 0;
      #pragma unroll
      for (int k = 0; k < H8; ++k) r |= s_z8[tid*H8 + k];
      z9[(size_t)t*N_FEAT + b*C3 + tid] = (float)r;
    }
    __syncthreads();
  }
}

// ---- F2: readout head for all 30 steps (closed-form tail when dead) +
//      weight-clip outputs ----
__global__ __launch_bounds__(NTHR) void f2_head(
    const float* __restrict__ z9,
    const float* __restrict__ fc1_w, const float* __restrict__ fc1_b,
    const float* __restrict__ out_w, const float* __restrict__ out_b,
    const float* __restrict__ w1,    const float* __restrict__ w2,
    float* __restrict__ out, const int* alive_flag)
{
  const int tid = threadIdx.x;
  const int gid = blockIdx.x*NTHR + tid;
  const int gsz = gridDim.x*NTHR;
  float* out_w1 = out + T_STEPS*N_FEAT;
  float* out_w2 = out_w1 + C1*25;
  for (int i = gid; i < C1*25;     i += gsz) out_w1[i] = fminf(fmaxf(w1[i], 0.f), 1.f);
  for (int i = gid; i < C2*C1*256; i += gsz) out_w2[i] = fminf(fmaxf(w2[i], 0.f), 1.f);
  if (blockIdx.x != 0) return;

  __shared__ float s_feat[N_FEAT], s_h[64], s_li[10], s_lv[10];
  __shared__ float s_tail[T_STEPS*10];
  if (tid < 10) { s_li[tid] = 0.f; s_lv[tid] = 0.f; }
  __syncthreads();
  const bool alive = (*alive_flag != 0);
  const int tmax = alive ? T_STEPS : 1;

  for (int t = 0; t < tmax; ++t) {
    for (int i = tid; i < N_FEAT; i += NTHR) s_feat[i] = z9[(size_t)t*N_FEAT + i];
    __syncthreads();
    {
      int o = tid >> 2, q = tid & 3;            // 4 lanes per fc1 output
      if (o < 50) {
        const float* wr = fc1_w + (size_t)o*N_FEAT + q*80;
        const float* fr = s_feat + q*80;
        float s = 0.f;
        for (int j = 0; j < 80; ++j) s = fmaf(fr[j], wr[j], s);
        s += __shfl_xor(s, 1, 64);
        s += __shfl_xor(s, 2, 64);
        if (q == 0) s_h[o] = fmaxf(s + fc1_b[o], 0.f);
      }
    }
    __syncthreads();
    if (tid < 10) {
      float idec = s_li[tid]*0.8f;              // 1 - dt*tau_syn_inv
      float vnew = s_lv[tid] + 0.1f*(idec - s_lv[tid]);
      float acc = idec + out_b[tid];
      for (int k = 0; k < 50; ++k) acc = fmaf(s_h[k], out_w[tid*50 + k], acc);
      s_li[tid] = acc;
      s_lv[tid] = vnew;
    }
    __syncthreads();
    float* vt = out + (size_t)t*N_FEAT;
    for (int i = tid; i < N_FEAT; i += NTHR) vt[i] = s_lv[i % 10];
    __syncthreads();
  }

  if (!alive) {                                 // closed-form tail t=1..29
    if (tid < 50) s_h[tid] = fmaxf(fc1_b[tid], 0.f);
    __syncthreads();
    if (tid < 10) {
      float c = out_b[tid];
      for (int k = 0; k < 50; ++k) c = fmaf(s_h[k], out_w[tid*50 + k], c);
      float li = s_li[tid], lv = s_lv[tid];
      for (int tt = 1; tt < T_STEPS; ++tt) {
        float idec = li*0.8f;
        lv = lv + 0.1f*(idec - lv);
        li = idec + c;
        s_tail[(tt - 1)*10 + tid] = lv;
      }
    }
    __syncthreads();
    int nrem = (T_STEPS - 1)*N_FEAT;
    float* vt = out + (size_t)N_FEAT;
    for (int i = tid; i < nrem; i += NTHR)
      vt[i] = s_tail[(i/N_FEAT)*10 + (i % 10)];
  }
}

extern "C" void kernel_launch(void* const* d_in, const int* in_sizes, int n_in,
                              void* d_out, int out_size, void* d_ws, size_t ws_size,
                              hipStream_t stream) {
  const float* x      = (const float*)d_in[0];
  const float* w1     = (const float*)d_in[1];
  const float* w2     = (const float*)d_in[2];
  const float* w3     = (const float*)d_in[3];
  const float* fc1_w  = (const float*)d_in[4];
  const float* fc1_b  = (const float*)d_in[5];
  const float* out_w  = (const float*)d_in[6];
  const float* out_b  = (const float*)d_in[7];
  float* out = (float*)d_out;   // [volts 30*320 | w1 100 | w2 20480]

  char* p = (char*)d_ws;
  float* v1 = (float*)p;                  p += (size_t)N_V1*4;
  float* z9 = (float*)p;                  p += (size_t)T_STEPS*N_FEAT*4;
  int* alive_flag = (int*)p;              p += 4;
  p += 60;                                // pad to 64B
  unsigned char* m1 = (unsigned char*)p;  p += N_V1;
  unsigned char* z2 = (unsigned char*)p;  p += N_V1;
  unsigned char* z3 = (unsigned char*)p;  p += N_Z3;
  unsigned char* z5 = (unsigned char*)p;  p += N_V2;

  k1_conv1pool<<<975, NTHR, 0, stream>>>(x, w1, z3, alive_flag);   // N_POOL*8 threads
  k2_conv2<<<C2*BATCH, NTHR, 0, stream>>>(z3, w2, z5, alive_flag); // 640: (c,b) blocks
  k3_conv3<<<BATCH, NTHR, 0, stream>>>(z5, w3, z9);
  f1_fallback<<<BATCH, NTHR, 0, stream>>>(x, w1, w2, w3,
                                          v1, m1, z2, z9, alive_flag);
  f2_head<<<64, NTHR, 0, stream>>>(z9, fc1_w, fc1_b, out_w, out_b,
                                   w1, w2, out, alive_flag);
}

// Round 11
// 50.198 us; speedup vs baseline: 3.2882x; 1.1033x over previous
//
#include <hip/hip_runtime.h>

// ConvNet_STDP — 5 regular kernels, stream-ordered, NO cooperative launch.
//
// Verified (rounds 1-10, absmax 0.0):
//  * STDP provably inert -> weight outputs are clip(w_init, 0, 1).
//  * Network dies at t=0 for this input -> fast path computes only step 0;
//    gated per-batch fallback (f1) is exact for any input (self-contained).
//  * k2 history: 85/148/114/98/43us. Invariant: cost ~ DS-pipe instructions
//    per wave (ds_read AND __shfl lower to DS). R10 cut ds_reads 1088->6 but
//    kept 360 shfl (ds_swizzle) -> 43us.
//  * R11 fix: 64-lane reduce via DPP (row_shr 1/2/4/8 + row_bcast 15/31,
//    __builtin_amdgcn_update_dpp) -> pure VALU, 0 DS. DS/wave 366 -> 6.
//    Result lands in lane 63. Rounding order changes are safe: f1 guards
//    exactness; spike margins are O(100); absmax 0.0 across 3 orders.

#define T_STEPS 30
#define BATCH   32
#define H_IN    240
#define W_IN    160
#define C1      4
#define H1      236
#define W1O     156
#define H3      39
#define W3      25
#define C2      20
#define H2      24
#define W2O     10
#define C3      10
#define H8      8

#define N1PB   (C1*H1*W1O)         // 147,264 per-batch conv1 positions
#define N_V1   (BATCH*N1PB)        // 4,712,448
#define N_V2PB (C2*H2*W2O)         // 4,800
#define N_V2   (BATCH*N_V2PB)      // 153,600
#define Z3PB   (C1*H3*W3)          // 3,900
#define N_Z3   (BATCH*Z3PB)        // 124,800
#define N_POOL (BATCH*H3*W3)       // 31,200
#define N_FEAT (BATCH*C3)          // 320

#define NTHR 256

// 64-lane sum, pure VALU (DPP). Result valid in lane 63 only.
__device__ __forceinline__ float wave64_sum_dpp(float s) {
  s += __int_as_float(__builtin_amdgcn_update_dpp(0, __float_as_int(s), 0x111, 0xf, 0xf, true)); // row_shr:1
  s += __int_as_float(__builtin_amdgcn_update_dpp(0, __float_as_int(s), 0x112, 0xf, 0xf, true)); // row_shr:2
  s += __int_as_float(__builtin_amdgcn_update_dpp(0, __float_as_int(s), 0x114, 0xf, 0xf, true)); // row_shr:4
  s += __int_as_float(__builtin_amdgcn_update_dpp(0, __float_as_int(s), 0x118, 0xf, 0xf, true)); // row_shr:8
  s += __int_as_float(__builtin_amdgcn_update_dpp(0, __float_as_int(s), 0x142, 0xa, 0xf, true)); // row_bcast:15
  s += __int_as_float(__builtin_amdgcn_update_dpp(0, __float_as_int(s), 0x143, 0xc, 0xf, true)); // row_bcast:31
  return s;
}

// ---- K1: fused conv1+pool1 (t=0, stateless) -> z3; init alive_flag ----
__global__ __launch_bounds__(NTHR) void k1_conv1pool(
    const float* __restrict__ x, const float* __restrict__ w1,
    unsigned char* __restrict__ z3, int* alive_flag)
{
  __shared__ float s_w1[C1*25];
  for (int i = threadIdx.x; i < C1*25; i += NTHR) s_w1[i] = w1[i];
  __syncthreads();
  int it = blockIdx.x*NTHR + threadIdx.x;
  if (it == 0) *alive_flag = 0;
  int o = it >> 3, q = it & 7;
  int px = o % W3; int tt = o / W3;
  int py = tt % H3; int b = tt / H3;
  unsigned mask = 0;
  if (q < 7) {
    const float* xb = x + (size_t)b*H_IN*W_IN;
    int ybase = py*6 + q;                       // this lane's window row
    float acc[C1][7];
    #pragma unroll
    for (int c = 0; c < C1; ++c)
      #pragma unroll
      for (int wx = 0; wx < 7; ++wx) acc[c][wx] = 0.f;
    #pragma unroll
    for (int i = 0; i < 5; ++i) {
      const float* xp = xb + (size_t)(ybase + i)*W_IN + px*6;
      float xr[11];
      #pragma unroll
      for (int k = 0; k < 11; ++k) xr[k] = xp[k];
      #pragma unroll
      for (int j = 0; j < 5; ++j) {
        float w0 = s_w1[ 0 + i*5 + j];
        float w1v = s_w1[25 + i*5 + j];
        float w2v = s_w1[50 + i*5 + j];
        float w3v = s_w1[75 + i*5 + j];
        #pragma unroll
        for (int wx = 0; wx < 7; ++wx) {
          float xv = xr[wx + j];
          acc[0][wx] = fmaf(xv, w0,  acc[0][wx]);
          acc[1][wx] = fmaf(xv, w1v, acc[1][wx]);
          acc[2][wx] = fmaf(xv, w2v, acc[2][wx]);
          acc[3][wx] = fmaf(xv, w3v, acc[3][wx]);
        }
      }
    }
    #pragma unroll
    for (int c = 0; c < C1; ++c)
      #pragma unroll
      for (int wx = 0; wx < 7; ++wx)
        mask |= (acc[c][wx] >= 10.f) ? (1u << c) : 0u;
  }
  mask |= __shfl_xor(mask, 1, 64);
  mask |= __shfl_xor(mask, 2, 64);
  mask |= __shfl_xor(mask, 4, 64);
  if (q == 0 && o < N_POOL) {
    unsigned char* zp = z3 + (size_t)b*Z3PB + py*W3 + px;
    zp[0]        =  mask       & 1;
    zp[H3*W3]    = (mask >> 1) & 1;
    zp[2*H3*W3]  = (mask >> 2) & 1;
    zp[3*H3*W3]  = (mask >> 3) & 1;
  }
}

// ---- K2: conv2 + IAF(60) (t=0) -> z5; alive_flag. Weights in registers,
//      DPP reduce (0 DS in the hot loop beyond 6 mask reads/wave). ----
__global__ __launch_bounds__(NTHR) void k2_conv2(
    const unsigned char* __restrict__ z3, const float* __restrict__ w2,
    unsigned char* __restrict__ z5, int* alive_flag)
{
  __shared__ unsigned s_mask[C1*H3];            // 156 packed rows
  __shared__ int s_any[4];
  const int b = blockIdx.x & 31;                // grid = 640 = 20c x 32b
  const int c = blockIdx.x >> 5;
  const int tid = threadIdx.x;
  const int lane = tid & 63;
  const int wv = tid >> 6;
  if (tid < C1*H3) {                            // pack row tid (25 bytes -> 25 bits)
    const unsigned char* rp = z3 + (size_t)b*Z3PB + tid*W3;
    unsigned m = 0;
    #pragma unroll
    for (int k = 0; k < W3; ++k) m |= (rp[k] ? 1u : 0u) << k;
    s_mask[tid] = m;
  }
  float wreg[16];                               // 4 coalesced float4 loads
  {
    const float4* wp = (const float4*)(w2 + (size_t)c*C1*256 + lane*16);
    #pragma unroll
    for (int k = 0; k < 4; ++k) {
      float4 v = wp[k];
      wreg[4*k+0] = v.x; wreg[4*k+1] = v.y; wreg[4*k+2] = v.z; wreg[4*k+3] = v.w;
    }
  }
  __syncthreads();
  const int mrow = (lane >> 4)*H3 + (lane & 15);   // ci*H3 + i (lane-fixed)
  int surv = 0;
  for (int oy = wv*6; oy < wv*6 + 6; ++oy) {
    unsigned mw = s_mask[mrow + oy];            // 1 DS read / 10 outputs
    #pragma unroll
    for (int ox = 0; ox < 10; ++ox) {
      unsigned mm = mw >> ox;
      float s = 0.f;
      #pragma unroll
      for (int j = 0; j < 16; ++j)
        s += (mm & (1u << j)) ? wreg[j] : 0.f;  // register taps, 64 lanes
      s = wave64_sum_dpp(s);                    // pure-VALU reduce -> lane 63
      if (lane == 63) {
        unsigned char sp = (s >= 60.0f) ? 1 : 0;
        z5[b*N_V2PB + c*(H2*W2O) + oy*W2O + ox] = sp;
        surv |= (sp == 0);
      }
    }
  }
  if (lane == 63) s_any[wv] = surv;
  __syncthreads();
  if (tid == 0 && (s_any[0] | s_any[1] | s_any[2] | s_any[3]))
    *alive_flag = 1;                            // plain store; dead case: no store
}

// ---- K3: conv3 (pool2 folded) + IAF(2) (t=0) -> z9[0]. One block/batch ----
__global__ __launch_bounds__(NTHR) void k3_conv3(
    const unsigned char* __restrict__ z5, const float* __restrict__ w3,
    float* __restrict__ z9)
{
  const int b = blockIdx.x, tid = threadIdx.x;
  __shared__ unsigned int s_z5w[N_V2PB/4];
  __shared__ unsigned char s_z8[C3*H8];
  const unsigned int* zsrc = (const unsigned int*)(z5 + (size_t)b*N_V2PB);
  for (int i = tid; i < N_V2PB/4; i += NTHR) s_z5w[i] = zsrc[i];
  __syncthreads();
  const unsigned char* sz = (const unsigned char*)s_z5w;
  for (int it = tid; it < C3*H8*4; it += NTHR) {
    int o = it >> 2, g = it & 3;                // 5-channel group per lane
    int c3 = o >> 3, oy = o & 7;
    float s = 0.f;
    for (int ci = g*5; ci < g*5 + 5; ++ci) {
      const unsigned char* zp = sz + ci*H2*W2O;
      const float* wp = w3 + ((size_t)c3*C2 + ci)*25;
      #pragma unroll
      for (int i = 0; i < 5; ++i) {
        const unsigned char* r0 = zp + (2*(oy + i))*W2O;
        const unsigned char* r1 = r0 + W2O;
        #pragma unroll
        for (int j = 0; j < 5; ++j) {
          unsigned char zv = r0[2*j] | r0[2*j+1] | r1[2*j] | r1[2*j+1];
          s = fmaf((float)zv, wp[i*5 + j], s);
        }
      }
    }
    s += __shfl_xor(s, 1, 64);
    s += __shfl_xor(s, 2, 64);
    if (g == 0) s_z8[o] = (s >= 2.0f) ? 1 : 0;
  }
  __syncthreads();
  if (tid < C3) {
    unsigned char r = 0;
    #pragma unroll
    for (int k = 0; k < H8; ++k) r |= s_z8[tid*H8 + k];
    z9[b*C3 + tid] = (float)r;                  // z9[t=0][b][c]
  }
}

// ---- F1: gated exact fallback — SELF-CONTAINED per-batch recompute of t=0
//      (conv1/pool/conv2/conv3/z9[0], exact reference order) + t=1..29
//      recurrence. Returns immediately when alive_flag==0 (measured case). ----
__global__ __launch_bounds__(NTHR) void f1_fallback(
    const float* __restrict__ x,  const float* __restrict__ w1,
    const float* __restrict__ w2, const float* __restrict__ w3,
    float* v1, unsigned char* m1, unsigned char* z2,
    float* __restrict__ z9, const int* alive_flag)
{
  if (*alive_flag == 0) return;
  const int b = blockIdx.x, tid = threadIdx.x;
  __shared__ float s_w1[C1*25];
  __shared__ unsigned char s_z3[Z3PB];
  __shared__ float s_v2[N_V2PB];
  __shared__ unsigned char s_m2[N_V2PB], s_z5[N_V2PB];
  __shared__ float s_v3[C3*H8];
  __shared__ unsigned char s_m3[C3*H8], s_z8[C3*H8];

  for (int i = tid; i < C1*25; i += NTHR) s_w1[i] = w1[i];
  float* v1b = v1 + (size_t)b*N1PB;
  unsigned char* m1b = m1 + (size_t)b*N1PB;
  unsigned char* z2b = z2 + (size_t)b*N1PB;
  __syncthreads();

  // t=0: conv1 state (exact order). Fired at t=0 <=> m1b==0.
  const float* x0 = x + (size_t)b*H_IN*W_IN;
  for (int idx = tid; idx < N1PB; idx += NTHR) {
    int xw = idx % W1O; int r = idx / W1O;
    int y  = r % H1;    int c = r / H1;
    const float* xp = x0 + (size_t)y*W_IN + xw;
    const float* wp = s_w1 + c*25;
    float s = 0.f;
    #pragma unroll
    for (int i = 0; i < 5; ++i)
      #pragma unroll
      for (int j = 0; j < 5; ++j) s = fmaf(xp[i*W_IN + j], wp[i*5 + j], s);
    bool z = (s >= 10.0f);
    v1b[idx] = z ? 0.f : s;
    m1b[idx] = z ? 0 : 1;
  }
  __syncthreads();
  // t=0: pool1 from m1b (spike <=> mask cleared at t=0)
  for (int i = tid; i < Z3PB; i += NTHR) {
    int px = i % W3; int r = i / W3;
    int py = r % H3; int cc = r / H3;
    const unsigned char* p = m1b + ((size_t)cc*H1 + py*6)*W1O + px*6;
    unsigned char rr = 0;
    #pragma unroll
    for (int ii = 0; ii < 7; ++ii)
      #pragma unroll
      for (int jj = 0; jj < 7; ++jj) rr |= (p[ii*W1O + jj] == 0) ? 1 : 0;
    s_z3[i] = rr;
  }
  __syncthreads();
  // t=0: conv2 state + exact z5
  for (int o = tid; o < N_V2PB; o += NTHR) {
    int c  = o / (H2*W2O);
    int r  = o - c*(H2*W2O);
    int oy = r / W2O, ox = r - (r/W2O)*W2O;
    const float* wb = w2 + (size_t)c*C1*256;
    float s = 0.f;
    for (int ci = 0; ci < C1; ++ci)
      for (int i = 0; i < 16; ++i) {
        const unsigned char* ip = s_z3 + (ci*H3 + oy + i)*W3 + ox;
        const float* wp = wb + ci*256 + i*16;
        #pragma unroll
        for (int j = 0; j < 16; ++j) s = fmaf((float)ip[j], wp[j], s);
      }
    bool z = (s >= 60.0f);
    s_v2[o] = z ? 0.f : s;
    s_m2[o] = z ? 0 : 1;
    s_z5[o] = z ? 1 : 0;                        // t=0: m=1 -> spike = z
  }
  __syncthreads();
  // t=0: conv3 state + z8 (from exact z5)
  for (int o = tid; o < C3*H8; o += NTHR) {
    int c3 = o >> 3, oy = o & 7;
    float s = 0.f;
    for (int ci = 0; ci < C2; ++ci) {
      const unsigned char* zp = s_z5 + ci*H2*W2O;
      const float* wp = w3 + ((size_t)c3*C2 + ci)*25;
      #pragma unroll
      for (int i = 0; i < 5; ++i) {
        const unsigned char* r0 = zp + (2*(oy + i))*W2O;
        const unsigned char* r1 = r0 + W2O;
        #pragma unroll
        for (int j = 0; j < 5; ++j) {
          unsigned char zv = r0[2*j] | r0[2*j+1] | r1[2*j] | r1[2*j+1];
          s = fmaf((float)zv, wp[i*5 + j], s);
        }
      }
    }
    bool z = (s >= 2.0f);
    s_v3[o] = z ? 0.f : s;
    s_m3[o] = z ? 0 : 1;
    s_z8[o] = z ? 1 : 0;                        // t=0: m=1
  }
  __syncthreads();
  if (tid < C3) {                               // exact z9[0] overwrites k3's
    unsigned char r = 0;
    #pragma unroll
    for (int k = 0; k < H8; ++k) r |= s_z8[tid*H8 + k];
    z9[b*C3 + tid] = (float)r;
  }
  __syncthreads();

  // exact recurrence t = 1..29 for this batch
  for (int t = 1; t < T_STEPS; ++t) {
    const float* xt = x + ((size_t)t*BATCH + b)*H_IN*W_IN;
    for (int idx = tid; idx < N1PB; idx += NTHR) {        // conv1+IAF
      int xw = idx % W1O; int r = idx / W1O;
      int y  = r % H1;    int c = r / H1;
      const float* xp = xt + (size_t)y*W_IN + xw;
      const float* wp = s_w1 + c*25;
      float s = 0.f;
      #pragma unroll
      for (int i = 0; i < 5; ++i)
        #pragma unroll
        for (int j = 0; j < 5; ++j) s = fmaf(xp[i*W_IN + j], wp[i*5 + j], s);
      float v = v1b[idx] + s;
      bool  z = (v >= 10.0f);
      v1b[idx] = z ? 0.f : v;
      unsigned char m = m1b[idx];
      z2b[idx] = (z && m) ? 1 : 0;
      m1b[idx] = (m && !z) ? 1 : 0;
    }
    __syncthreads();
    for (int i = tid; i < Z3PB; i += NTHR) {              // pool1 = OR
      int px = i % W3; int r = i / W3;
      int py = r % H3; int c = r / H3;
      const unsigned char* p = z2b + ((size_t)c*H1 + py*6)*W1O + px*6;
      unsigned char rr = 0;
      #pragma unroll
      for (int ii = 0; ii < 7; ++ii)
        #pragma unroll
        for (int jj = 0; jj < 7; ++jj) rr |= p[ii*W1O + jj];
      s_z3[i] = rr;
    }
    __syncthreads();
    for (int o = tid; o < N_V2PB; o += NTHR) {            // conv2+IAF
      int c  = o / (H2*W2O);
      int r  = o - c*(H2*W2O);
      int oy = r / W2O, ox = r - (r/W2O)*W2O;
      const float* wb = w2 + (size_t)c*C1*256;
      float s = 0.f;
      for (int ci = 0; ci < C1; ++ci)
        for (int i = 0; i < 16; ++i) {
          const unsigned char* ip = s_z3 + (ci*H3 + oy + i)*W3 + ox;
          const float* wp = wb + ci*256 + i*16;
          #pragma unroll
          for (int j = 0; j < 16; ++j) s = fmaf((float)ip[j], wp[j], s);
        }
      float v = s_v2[o] + s;
      bool  z = (v >= 60.0f);
      s_v2[o] = z ? 0.f : v;
      unsigned char m = s_m2[o];
      s_z5[o] = (z && m) ? 1 : 0;
      s_m2[o] = (m && !z) ? 1 : 0;
    }
    __syncthreads();
    for (int o = tid; o < C3*H8; o += NTHR) {             // conv3+IAF (pool folded)
      int c3 = o >> 3, oy = o & 7;
      float s = 0.f;
      for (int ci = 0; ci < C2; ++ci) {
        const unsigned char* zp = s_z5 + ci*H2*W2O;
        const float* wp = w3 + ((size_t)c3*C2 + ci)*25;
        #pragma unroll
        for (int i = 0; i < 5; ++i) {
          const unsigned char* r0 = zp + (2*(oy + i))*W2O;
          const unsigned char* r1 = r0 + W2O;
          #pragma unroll
          for (int j = 0; j < 5; ++j) {
            unsigned char zv = r0[2*j] | r0[2*j+1] | r1[2*j] | r1[2*j+1];
            s = fmaf((float)zv, wp[i*5 + j], s);
          }
        }
      }
      float v = s_v3[o] + s;
      bool  z = (v >= 2.0f);
      s_v3[o] = z ? 0.f : v;
      unsigned char m = s_m3[o];
      s_z8[o] = (z && m) ? 1 : 0;
      s_m3[o] = (m && !z) ? 1 : 0;
    }
    __syncthreads();
    if (tid < C3) {                                       // z9[t][b][c]
      unsigned char r = 0;
      #pragma unroll
      for (int k = 0; k < H8; ++k) r |= s_z8[tid*H8 + k];
      z9[(size_t)t*N_FEAT + b*C3 + tid] = (float)r;
    }
    __syncthreads();
  }
}

// ---- F2: readout head for all 30 steps (closed-form tail when dead) +
//      weight-clip outputs ----
__global__ __launch_bounds__(NTHR) void f2_head(
    const float* __restrict__ z9,
    const float* __restrict__ fc1_w, const float* __restrict__ fc1_b,
    const float* __restrict__ out_w, const float* __restrict__ out_b,
    const float* __restrict__ w1,    const float* __restrict__ w2,
    float* __restrict__ out, const int* alive_flag)
{
  const int tid = threadIdx.x;
  const int gid = blockIdx.x*NTHR + tid;
  const int gsz = gridDim.x*NTHR;
  float* out_w1 = out + T_STEPS*N_FEAT;
  float* out_w2 = out_w1 + C1*25;
  for (int i = gid; i < C1*25;     i += gsz) out_w1[i] = fminf(fmaxf(w1[i], 0.f), 1.f);
  for (int i = gid; i < C2*C1*256; i += gsz) out_w2[i] = fminf(fmaxf(w2[i], 0.f), 1.f);
  if (blockIdx.x != 0) return;

  __shared__ float s_feat[N_FEAT], s_h[64], s_li[10], s_lv[10];
  __shared__ float s_tail[T_STEPS*10];
  if (tid < 10) { s_li[tid] = 0.f; s_lv[tid] = 0.f; }
  __syncthreads();
  const bool alive = (*alive_flag != 0);
  const int tmax = alive ? T_STEPS : 1;

  for (int t = 0; t < tmax; ++t) {
    for (int i = tid; i < N_FEAT; i += NTHR) s_feat[i] = z9[(size_t)t*N_FEAT + i];
    __syncthreads();
    {
      int o = tid >> 2, q = tid & 3;            // 4 lanes per fc1 output
      if (o < 50) {
        const float* wr = fc1_w + (size_t)o*N_FEAT + q*80;
        const float* fr = s_feat + q*80;
        float s = 0.f;
        for (int j = 0; j < 80; ++j) s = fmaf(fr[j], wr[j], s);
        s += __shfl_xor(s, 1, 64);
        s += __shfl_xor(s, 2, 64);
        if (q == 0) s_h[o] = fmaxf(s + fc1_b[o], 0.f);
      }
    }
    __syncthreads();
    if (tid < 10) {
      float idec = s_li[tid]*0.8f;              // 1 - dt*tau_syn_inv
      float vnew = s_lv[tid] + 0.1f*(idec - s_lv[tid]);
      float acc = idec + out_b[tid];
      for (int k = 0; k < 50; ++k) acc = fmaf(s_h[k], out_w[tid*50 + k], acc);
      s_li[tid] = acc;
      s_lv[tid] = vnew;
    }
    __syncthreads();
    float* vt = out + (size_t)t*N_FEAT;
    for (int i = tid; i < N_FEAT; i += NTHR) vt[i] = s_lv[i % 10];
    __syncthreads();
  }

  if (!alive) {                                 // closed-form tail t=1..29
    if (tid < 50) s_h[tid] = fmaxf(fc1_b[tid], 0.f);
    __syncthreads();
    if (tid < 10) {
      float c = out_b[tid];
      for (int k = 0; k < 50; ++k) c = fmaf(s_h[k], out_w[tid*50 + k], c);
      float li = s_li[tid], lv = s_lv[tid];
      for (int tt = 1; tt < T_STEPS; ++tt) {
        float idec = li*0.8f;
        lv = lv + 0.1f*(idec - lv);
        li = idec + c;
        s_tail[(tt - 1)*10 + tid] = lv;
      }
    }
    __syncthreads();
    int nrem = (T_STEPS - 1)*N_FEAT;
    float* vt = out + (size_t)N_FEAT;
    for (int i = tid; i < nrem; i += NTHR)
      vt[i] = s_tail[(i/N_FEAT)*10 + (i % 10)];
  }
}

extern "C" void kernel_launch(void* const* d_in, const int* in_sizes, int n_in,
                              void* d_out, int out_size, void* d_ws, size_t ws_size,
                              hipStream_t stream) {
  const float* x      = (const float*)d_in[0];
  const float* w1     = (const float*)d_in[1];
  const float* w2     = (const float*)d_in[2];
  const float* w3     = (const float*)d_in[3];
  const float* fc1_w  = (const float*)d_in[4];
  const float* fc1_b  = (const float*)d_in[5];
  const float* out_w  = (const float*)d_in[6];
  const float* out_b  = (const float*)d_in[7];
  float* out = (float*)d_out;   // [volts 30*320 | w1 100 | w2 20480]

  char* p = (char*)d_ws;
  float* v1 = (float*)p;                  p += (size_t)N_V1*4;
  float* z9 = (float*)p;                  p += (size_t)T_STEPS*N_FEAT*4;
  int* alive_flag = (int*)p;              p += 4;
  p += 60;                                // pad to 64B
  unsigned char* m1 = (unsigned char*)p;  p += N_V1;
  unsigned char* z2 = (unsigned char*)p;  p += N_V1;
  unsigned char* z3 = (unsigned char*)p;  p += N_Z3;
  unsigned char* z5 = (unsigned char*)p;  p += N_V2;

  k1_conv1pool<<<975, NTHR, 0, stream>>>(x, w1, z3, alive_flag);   // N_POOL*8 threads
  k2_conv2<<<C2*BATCH, NTHR, 0, stream>>>(z3, w2, z5, alive_flag); // 640: (c,b) blocks
  k3_conv3<<<BATCH, NTHR, 0, stream>>>(z5, w3, z9);
  f1_fallback<<<BATCH, NTHR, 0, stream>>>(x, w1, w2, w3,
                                          v1, m1, z2, z9, alive_flag);
  f2_head<<<64, NTHR, 0, stream>>>(z9, fc1_w, fc1_b, out_w, out_b,
                                   w1, w2, out, alive_flag);
}

// Round 12
// 46.710 us; speedup vs baseline: 3.5337x; 1.0747x over previous
//
#include <hip/hip_runtime.h>

// ConvNet_STDP — 4 regular kernels, stream-ordered, NO cooperative launch.
//
// Verified (rounds 1-11, absmax 0.0):
//  * STDP provably inert -> weight outputs are clip(w_init, 0, 1).
//  * Network dies at t=0 for this input -> fast path computes only step 0;
//    gated per-batch fallback (f1, self-contained) is exact for any input.
//  * k2 history: 85/148/114/98/43/38us across FIVE bodies. Last invariant:
//    occupancy ~3 waves/CU (640 4-wave blocks, VGPR 132) -> dependent-chain
//    latency unhidden (issue floor ~5us, measured 38).
//  * R12 fix: grid (b,c,oy)=3840 blocks x 4 waves, each wave = one output
//    row; lanes pack their mask row straight from global (25 ubyte loads);
//    no LDS, no syncthreads -> ~60 waves/CU. Mask bits, weights, lane->tap
//    map, and DPP order identical to R11 -> z5/flag bitwise unchanged.
//  * Launches 5->4: k3+f1 fused (both per-batch), weight-clip moved to k1,
//    f2 now a single block.

#define T_STEPS 30
#define BATCH   32
#define H_IN    240
#define W_IN    160
#define C1      4
#define H1      236
#define W1O     156
#define H3      39
#define W3      25
#define C2      20
#define H2      24
#define W2O     10
#define C3      10
#define H8      8

#define N1PB   (C1*H1*W1O)         // 147,264 per-batch conv1 positions
#define N_V1   (BATCH*N1PB)        // 4,712,448
#define N_V2PB (C2*H2*W2O)         // 4,800
#define N_V2   (BATCH*N_V2PB)      // 153,600
#define Z3PB   (C1*H3*W3)          // 3,900
#define N_Z3   (BATCH*Z3PB)        // 124,800
#define N_POOL (BATCH*H3*W3)       // 31,200
#define N_FEAT (BATCH*C3)          // 320

#define NTHR 256
#define K1_BLOCKS 975              // N_POOL*8 / 256 exactly

// 64-lane sum, pure VALU (DPP). Result valid in lane 63 only.
__device__ __forceinline__ float wave64_sum_dpp(float s) {
  s += __int_as_float(__builtin_amdgcn_update_dpp(0, __float_as_int(s), 0x111, 0xf, 0xf, true)); // row_shr:1
  s += __int_as_float(__builtin_amdgcn_update_dpp(0, __float_as_int(s), 0x112, 0xf, 0xf, true)); // row_shr:2
  s += __int_as_float(__builtin_amdgcn_update_dpp(0, __float_as_int(s), 0x114, 0xf, 0xf, true)); // row_shr:4
  s += __int_as_float(__builtin_amdgcn_update_dpp(0, __float_as_int(s), 0x118, 0xf, 0xf, true)); // row_shr:8
  s += __int_as_float(__builtin_amdgcn_update_dpp(0, __float_as_int(s), 0x142, 0xa, 0xf, true)); // row_bcast:15
  s += __int_as_float(__builtin_amdgcn_update_dpp(0, __float_as_int(s), 0x143, 0xc, 0xf, true)); // row_bcast:31
  return s;
}

// ---- K1: fused conv1+pool1 (t=0, stateless) -> z3; init alive_flag;
//      weight-clip outputs (independent of everything else) ----
__global__ __launch_bounds__(NTHR) void k1_conv1pool(
    const float* __restrict__ x, const float* __restrict__ w1,
    const float* __restrict__ w2,
    unsigned char* __restrict__ z3, int* alive_flag,
    float* __restrict__ out_w1, float* __restrict__ out_w2)
{
  __shared__ float s_w1[C1*25];
  for (int i = threadIdx.x; i < C1*25; i += NTHR) s_w1[i] = w1[i];
  __syncthreads();
  int it = blockIdx.x*NTHR + threadIdx.x;
  const int gsz = K1_BLOCKS*NTHR;
  if (it == 0) *alive_flag = 0;
  for (int i = it; i < C1*25;     i += gsz) out_w1[i] = fminf(fmaxf(w1[i], 0.f), 1.f);
  for (int i = it; i < C2*C1*256; i += gsz) out_w2[i] = fminf(fmaxf(w2[i], 0.f), 1.f);
  int o = it >> 3, q = it & 7;
  int px = o % W3; int tt = o / W3;
  int py = tt % H3; int b = tt / H3;
  unsigned mask = 0;
  if (q < 7) {
    const float* xb = x + (size_t)b*H_IN*W_IN;
    int ybase = py*6 + q;                       // this lane's window row
    float acc[C1][7];
    #pragma unroll
    for (int c = 0; c < C1; ++c)
      #pragma unroll
      for (int wx = 0; wx < 7; ++wx) acc[c][wx] = 0.f;
    #pragma unroll
    for (int i = 0; i < 5; ++i) {
      const float* xp = xb + (size_t)(ybase + i)*W_IN + px*6;
      float xr[11];
      #pragma unroll
      for (int k = 0; k < 11; ++k) xr[k] = xp[k];
      #pragma unroll
      for (int j = 0; j < 5; ++j) {
        float w0 = s_w1[ 0 + i*5 + j];
        float w1v = s_w1[25 + i*5 + j];
        float w2v = s_w1[50 + i*5 + j];
        float w3v = s_w1[75 + i*5 + j];
        #pragma unroll
        for (int wx = 0; wx < 7; ++wx) {
          float xv = xr[wx + j];
          acc[0][wx] = fmaf(xv, w0,  acc[0][wx]);
          acc[1][wx] = fmaf(xv, w1v, acc[1][wx]);
          acc[2][wx] = fmaf(xv, w2v, acc[2][wx]);
          acc[3][wx] = fmaf(xv, w3v, acc[3][wx]);
        }
      }
    }
    #pragma unroll
    for (int c = 0; c < C1; ++c)
      #pragma unroll
      for (int wx = 0; wx < 7; ++wx)
        mask |= (acc[c][wx] >= 10.f) ? (1u << c) : 0u;
  }
  mask |= __shfl_xor(mask, 1, 64);
  mask |= __shfl_xor(mask, 2, 64);
  mask |= __shfl_xor(mask, 4, 64);
  if (q == 0 && o < N_POOL) {
    unsigned char* zp = z3 + (size_t)b*Z3PB + py*W3 + px;
    zp[0]        =  mask       & 1;
    zp[H3*W3]    = (mask >> 1) & 1;
    zp[2*H3*W3]  = (mask >> 2) & 1;
    zp[3*H3*W3]  = (mask >> 3) & 1;
  }
}

// ---- K2: conv2 + IAF(60) (t=0) -> z5; alive_flag. One wave = one output
//      row; no LDS, no sync; mask packed from global per lane. ----
__global__ __launch_bounds__(NTHR) void k2_conv2(
    const unsigned char* __restrict__ z3, const float* __restrict__ w2,
    unsigned char* __restrict__ z5, int* alive_flag)
{
  // grid = 3840 = 32 b x 20 c x 6 oy-groups; wave wv handles oy = g*4+wv
  const int b  = blockIdx.x & 31;
  const int cg = blockIdx.x >> 5;               // 0..119
  const int c  = cg / 6;
  const int g  = cg - c*6;
  const int tid = threadIdx.x;
  const int lane = tid & 63;
  const int wv = tid >> 6;
  const int oy = g*4 + wv;                      // 0..23
  const int ci = lane >> 4, ii = lane & 15;
  float wreg[16];                               // w2[c][ci][ii][0..16)
  {
    const float4* wp = (const float4*)(w2 + ((size_t)c*C1 + ci)*256 + ii*16);
    #pragma unroll
    for (int k = 0; k < 4; ++k) {
      float4 v = wp[k];
      wreg[4*k+0] = v.x; wreg[4*k+1] = v.y; wreg[4*k+2] = v.z; wreg[4*k+3] = v.w;
    }
  }
  unsigned mw = 0;                              // packed 25-bit window row
  {
    const unsigned char* rp = z3 + (size_t)b*Z3PB + (ci*H3 + oy + ii)*W3;
    #pragma unroll
    for (int k = 0; k < W3; ++k) mw |= (rp[k] ? 1u : 0u) << k;
  }
  int surv = 0;
  #pragma unroll
  for (int ox = 0; ox < 10; ++ox) {
    unsigned mm = mw >> ox;
    float s = 0.f;
    #pragma unroll
    for (int j = 0; j < 16; ++j)
      s += (mm & (1u << j)) ? wreg[j] : 0.f;    // register taps
    s = wave64_sum_dpp(s);                      // pure-VALU reduce -> lane 63
    if (lane == 63) {
      unsigned char sp = (s >= 60.0f) ? 1 : 0;
      z5[b*N_V2PB + c*(H2*W2O) + oy*W2O + ox] = sp;
      surv |= (sp == 0);
    }
  }
  if (lane == 63 && surv) *alive_flag = 1;      // plain store; dead: no store
}

// ---- K3F1: per-batch. Part 1 (always): conv3 (pool2 folded) + IAF(2) at
//      t=0 -> z9[0]. Part 2 (gated, exact, self-contained): recompute t=0
//      state from x and run t=1..29 recurrence. ----
__global__ __launch_bounds__(NTHR) void k3f1(
    const unsigned char* __restrict__ z5g, const float* __restrict__ w3,
    const float* __restrict__ x,  const float* __restrict__ w1,
    const float* __restrict__ w2,
    float* v1, unsigned char* m1, unsigned char* z2,
    float* __restrict__ z9, const int* alive_flag)
{
  const int b = blockIdx.x, tid = threadIdx.x;
  __shared__ float s_w1[C1*25];
  __shared__ unsigned char s_z3[Z3PB];
  __shared__ float s_v2[N_V2PB];
  __shared__ unsigned char s_m2[N_V2PB], s_z5[N_V2PB];
  __shared__ float s_v3[C3*H8];
  __shared__ unsigned char s_m3[C3*H8], s_z8[C3*H8];

  // ---- Part 1: k3 from K2's z5 (fast path's z9[0]) ----
  {
    const unsigned int* zsrc = (const unsigned int*)(z5g + (size_t)b*N_V2PB);
    unsigned int* dst = (unsigned int*)s_z5;
    for (int i = tid; i < N_V2PB/4; i += NTHR) dst[i] = zsrc[i];
  }
  __syncthreads();
  for (int it = tid; it < C3*H8*4; it += NTHR) {
    int o = it >> 2, g = it & 3;                // 5-channel group per lane
    int c3 = o >> 3, oy = o & 7;
    float s = 0.f;
    for (int ci = g*5; ci < g*5 + 5; ++ci) {
      const unsigned char* zp = s_z5 + ci*H2*W2O;
      const float* wp = w3 + ((size_t)c3*C2 + ci)*25;
      #pragma unroll
      for (int i = 0; i < 5; ++i) {
        const unsigned char* r0 = zp + (2*(oy + i))*W2O;
        const unsigned char* r1 = r0 + W2O;
        #pragma unroll
        for (int j = 0; j < 5; ++j) {
          unsigned char zv = r0[2*j] | r0[2*j+1] | r1[2*j] | r1[2*j+1];
          s = fmaf((float)zv, wp[i*5 + j], s);
        }
      }
    }
    s += __shfl_xor(s, 1, 64);
    s += __shfl_xor(s, 2, 64);
    if (g == 0) s_z8[o] = (s >= 2.0f) ? 1 : 0;
  }
  __syncthreads();
  if (tid < C3) {
    unsigned char r = 0;
    #pragma unroll
    for (int k = 0; k < H8; ++k) r |= s_z8[tid*H8 + k];
    z9[b*C3 + tid] = (float)r;                  // z9[t=0][b][c]
  }

  // ---- Part 2: gated exact fallback ----
  if (*alive_flag == 0) return;
  __syncthreads();
  for (int i = tid; i < C1*25; i += NTHR) s_w1[i] = w1[i];
  float* v1b = v1 + (size_t)b*N1PB;
  unsigned char* m1b = m1 + (size_t)b*N1PB;
  unsigned char* z2b = z2 + (size_t)b*N1PB;
  __syncthreads();

  // t=0: conv1 state (exact order). Fired at t=0 <=> m1b==0.
  const float* x0 = x + (size_t)b*H_IN*W_IN;
  for (int idx = tid; idx < N1PB; idx += NTHR) {
    int xw = idx % W1O; int r = idx / W1O;
    int y  = r % H1;    int c = r / H1;
    const float* xp = x0 + (size_t)y*W_IN + xw;
    const float* wp = s_w1 + c*25;
    float s = 0.f;
    #pragma unroll
    for (int i = 0; i < 5; ++i)
      #pragma unroll
      for (int j = 0; j < 5; ++j) s = fmaf(xp[i*W_IN + j], wp[i*5 + j], s);
    bool z = (s >= 10.0f);
    v1b[idx] = z ? 0.f : s;
    m1b[idx] = z ? 0 : 1;
  }
  __syncthreads();
  // t=0: pool1 from m1b (spike <=> mask cleared at t=0)
  for (int i = tid; i < Z3PB; i += NTHR) {
    int px = i % W3; int r = i / W3;
    int py = r % H3; int cc = r / H3;
    const unsigned char* p = m1b + ((size_t)cc*H1 + py*6)*W1O + px*6;
    unsigned char rr = 0;
    #pragma unroll
    for (int ii = 0; ii < 7; ++ii)
      #pragma unroll
      for (int jj = 0; jj < 7; ++jj) rr |= (p[ii*W1O + jj] == 0) ? 1 : 0;
    s_z3[i] = rr;
  }
  __syncthreads();
  // t=0: conv2 state + exact z5
  for (int o = tid; o < N_V2PB; o += NTHR) {
    int c  = o / (H2*W2O);
    int r  = o - c*(H2*W2O);
    int oy = r / W2O, ox = r - (r/W2O)*W2O;
    const float* wb = w2 + (size_t)c*C1*256;
    float s = 0.f;
    for (int ci = 0; ci < C1; ++ci)
      for (int i = 0; i < 16; ++i) {
        const unsigned char* ip = s_z3 + (ci*H3 + oy + i)*W3 + ox;
        const float* wp = wb + ci*256 + i*16;
        #pragma unroll
        for (int j = 0; j < 16; ++j) s = fmaf((float)ip[j], wp[j], s);
      }
    bool z = (s >= 60.0f);
    s_v2[o] = z ? 0.f : s;
    s_m2[o] = z ? 0 : 1;
    s_z5[o] = z ? 1 : 0;                        // t=0: m=1 -> spike = z
  }
  __syncthreads();
  // t=0: conv3 state + z8 (from exact z5)
  for (int o = tid; o < C3*H8; o += NTHR) {
    int c3 = o >> 3, oy = o & 7;
    float s = 0.f;
    for (int ci = 0; ci < C2; ++ci) {
      const unsigned char* zp = s_z5 + ci*H2*W2O;
      const float* wp = w3 + ((size_t)c3*C2 + ci)*25;
      #pragma unroll
      for (int i = 0; i < 5; ++i) {
        const unsigned char* r0 = zp + (2*(oy + i))*W2O;
        const unsigned char* r1 = r0 + W2O;
        #pragma unroll
        for (int j = 0; j < 5; ++j) {
          unsigned char zv = r0[2*j] | r0[2*j+1] | r1[2*j] | r1[2*j+1];
          s = fmaf((float)zv, wp[i*5 + j], s);
        }
      }
    }
    bool z = (s >= 2.0f);
    s_v3[o] = z ? 0.f : s;
    s_m3[o] = z ? 0 : 1;
    s_z8[o] = z ? 1 : 0;                        // t=0: m=1
  }
  __syncthreads();
  if (tid < C3) {                               // exact z9[0] overwrites part 1
    unsigned char r = 0;
    #pragma unroll
    for (int k = 0; k < H8; ++k) r |= s_z8[tid*H8 + k];
    z9[b*C3 + tid] = (float)r;
  }
  __syncthreads();

  // exact recurrence t = 1..29 for this batch
  for (int t = 1; t < T_STEPS; ++t) {
    const float* xt = x + ((size_t)t*BATCH + b)*H_IN*W_IN;
    for (int idx = tid; idx < N1PB; idx += NTHR) {        // conv1+IAF
      int xw = idx % W1O; int r = idx / W1O;
      int y  = r % H1;    int c = r / H1;
      const float* xp = xt + (size_t)y*W_IN + xw;
      const float* wp = s_w1 + c*25;
      float s = 0.f;
      #pragma unroll
      for (int i = 0; i < 5; ++i)
        #pragma unroll
        for (int j = 0; j < 5; ++j) s = fmaf(xp[i*W_IN + j], wp[i*5 + j], s);
      float v = v1b[idx] + s;
      bool  z = (v >= 10.0f);
      v1b[idx] = z ? 0.f : v;
      unsigned char m = m1b[idx];
      z2b[idx] = (z && m) ? 1 : 0;
      m1b[idx] = (m && !z) ? 1 : 0;
    }
    __syncthreads();
    for (int i = tid; i < Z3PB; i += NTHR) {              // pool1 = OR
      int px = i % W3; int r = i / W3;
      int py = r % H3; int c = r / H3;
      const unsigned char* p = z2b + ((size_t)c*H1 + py*6)*W1O + px*6;
      unsigned char rr = 0;
      #pragma unroll
      for (int ii = 0; ii < 7; ++ii)
        #pragma unroll
        for (int jj = 0; jj < 7; ++jj) rr |= p[ii*W1O + jj];
      s_z3[i] = rr;
    }
    __syncthreads();
    for (int o = tid; o < N_V2PB; o += NTHR) {            // conv2+IAF
      int c  = o / (H2*W2O);
      int r  = o - c*(H2*W2O);
      int oy = r / W2O, ox = r - (r/W2O)*W2O;
      const float* wb = w2 + (size_t)c*C1*256;
      float s = 0.f;
      for (int ci = 0; ci < C1; ++ci)
        for (int i = 0; i < 16; ++i) {
          const unsigned char* ip = s_z3 + (ci*H3 + oy + i)*W3 + ox;
          const float* wp = wb + ci*256 + i*16;
          #pragma unroll
          for (int j = 0; j < 16; ++j) s = fmaf((float)ip[j], wp[j], s);
        }
      float v = s_v2[o] + s;
      bool  z = (v >= 60.0f);
      s_v2[o] = z ? 0.f : v;
      unsigned char m = s_m2[o];
      s_z5[o] = (z && m) ? 1 : 0;
      s_m2[o] = (m && !z) ? 1 : 0;
    }
    __syncthreads();
    for (int o = tid; o < C3*H8; o += NTHR) {             // conv3+IAF (pool folded)
      int c3 = o >> 3, oy = o & 7;
      float s = 0.f;
      for (int ci = 0; ci < C2; ++ci) {
        const unsigned char* zp = s_z5 + ci*H2*W2O;
        const float* wp = w3 + ((size_t)c3*C2 + ci)*25;
        #pragma unroll
        for (int i = 0; i < 5; ++i) {
          const unsigned char* r0 = zp + (2*(oy + i))*W2O;
          const unsigned char* r1 = r0 + W2O;
          #pragma unroll
          for (int j = 0; j < 5; ++j) {
            unsigned char zv = r0[2*j] | r0[2*j+1] | r1[2*j] | r1[2*j+1];
            s = fmaf((float)zv, wp[i*5 + j], s);
          }
        }
      }
      float v = s_v3[o] + s;
      bool  z = (v >= 2.0f);
      s_v3[o] = z ? 0.f : v;
      unsigned char m = s_m3[o];
      s_z8[o] = (z && m) ? 1 : 0;
      s_m3[o] = (m && !z) ? 1 : 0;
    }
    __syncthreads();
    if (tid < C3) {                                       // z9[t][b][c]
      unsigned char r = 0;
      #pragma unroll
      for (int k = 0; k < H8; ++k) r |= s_z8[tid*H8 + k];
      z9[(size_t)t*N_FEAT + b*C3 + tid] = (float)r;
    }
    __syncthreads();
  }
}

// ---- F2: readout head, single block (closed-form tail when dead) ----
__global__ __launch_bounds__(NTHR) void f2_head(
    const float* __restrict__ z9,
    const float* __restrict__ fc1_w, const float* __restrict__ fc1_b,
    const float* __restrict__ out_w, const float* __restrict__ out_b,
    float* __restrict__ out, const int* alive_flag)
{
  const int tid = threadIdx.x;
  __shared__ float s_feat[N_FEAT], s_h[64], s_li[10], s_lv[10];
  __shared__ float s_tail[T_STEPS*10];
  if (tid < 10) { s_li[tid] = 0.f; s_lv[tid] = 0.f; }
  __syncthreads();
  const bool alive = (*alive_flag != 0);
  const int tmax = alive ? T_STEPS : 1;

  for (int t = 0; t < tmax; ++t) {
    for (int i = tid; i < N_FEAT; i += NTHR) s_feat[i] = z9[(size_t)t*N_FEAT + i];
    __syncthreads();
    {
      int o = tid >> 2, q = tid & 3;            // 4 lanes per fc1 output
      if (o < 50) {
        const float* wr = fc1_w + (size_t)o*N_FEAT + q*80;
        const float* fr = s_feat + q*80;
        float s = 0.f;
        for (int j = 0; j < 80; ++j) s = fmaf(fr[j], wr[j], s);
        s += __shfl_xor(s, 1, 64);
        s += __shfl_xor(s, 2, 64);
        if (q == 0) s_h[o] = fmaxf(s + fc1_b[o], 0.f);
      }
    }
    __syncthreads();
    if (tid < 10) {
      float idec = s_li[tid]*0.8f;              // 1 - dt*tau_syn_inv
      float vnew = s_lv[tid] + 0.1f*(idec - s_lv[tid]);
      float acc = idec + out_b[tid];
      for (int k = 0; k < 50; ++k) acc = fmaf(s_h[k], out_w[tid*50 + k], acc);
      s_li[tid] = acc;
      s_lv[tid] = vnew;
    }
    __syncthreads();
    float* vt = out + (size_t)t*N_FEAT;
    for (int i = tid; i < N_FEAT; i += NTHR) vt[i] = s_lv[i % 10];
    __syncthreads();
  }

  if (!alive) {                                 // closed-form tail t=1..29
    if (tid < 50) s_h[tid] = fmaxf(fc1_b[tid], 0.f);
    __syncthreads();
    if (tid < 10) {
      float c = out_b[tid];
      for (int k = 0; k < 50; ++k) c = fmaf(s_h[k], out_w[tid*50 + k], c);
      float li = s_li[tid], lv = s_lv[tid];
      for (int tt = 1; tt < T_STEPS; ++tt) {
        float idec = li*0.8f;
        lv = lv + 0.1f*(idec - lv);
        li = idec + c;
        s_tail[(tt - 1)*10 + tid] = lv;
      }
    }
    __syncthreads();
    int nrem = (T_STEPS - 1)*N_FEAT;
    float* vt = out + (size_t)N_FEAT;
    for (int i = tid; i < nrem; i += NTHR)
      vt[i] = s_tail[(i/N_FEAT)*10 + (i % 10)];
  }
}

extern "C" void kernel_launch(void* const* d_in, const int* in_sizes, int n_in,
                              void* d_out, int out_size, void* d_ws, size_t ws_size,
                              hipStream_t stream) {
  const float* x      = (const float*)d_in[0];
  const float* w1     = (const float*)d_in[1];
  const float* w2     = (const float*)d_in[2];
  const float* w3     = (const float*)d_in[3];
  const float* fc1_w  = (const float*)d_in[4];
  const float* fc1_b  = (const float*)d_in[5];
  const float* out_w  = (const float*)d_in[6];
  const float* out_b  = (const float*)d_in[7];
  float* out = (float*)d_out;   // [volts 30*320 | w1 100 | w2 20480]
  float* out_w1 = out + T_STEPS*N_FEAT;
  float* out_w2 = out_w1 + C1*25;

  char* p = (char*)d_ws;
  float* v1 = (float*)p;                  p += (size_t)N_V1*4;
  float* z9 = (float*)p;                  p += (size_t)T_STEPS*N_FEAT*4;
  int* alive_flag = (int*)p;              p += 4;
  p += 60;                                // pad to 64B
  unsigned char* m1 = (unsigned char*)p;  p += N_V1;
  unsigned char* z2 = (unsigned char*)p;  p += N_V1;
  unsigned char* z3 = (unsigned char*)p;  p += N_Z3;
  unsigned char* z5 = (unsigned char*)p;  p += N_V2;

  k1_conv1pool<<<K1_BLOCKS, NTHR, 0, stream>>>(x, w1, w2, z3, alive_flag,
                                               out_w1, out_w2);
  k2_conv2<<<BATCH*C2*6, NTHR, 0, stream>>>(z3, w2, z5, alive_flag); // 3840
  k3f1<<<BATCH, NTHR, 0, stream>>>(z5, w3, x, w1, w2,
                                   v1, m1, z2, z9, alive_flag);
  f2_head<<<1, NTHR, 0, stream>>>(z9, fc1_w, fc1_b, out_w, out_b,
                                  out, alive_flag);
}